// Round 1
// baseline (1289.944 us; speedup 1.0000x reference)
//
#include <hip/hip_runtime.h>

#define TT 16384      // tokens = B*S
#define DD 1024       // d_model
#define EE 32         // experts
#define ESS 128       // expert size
#define VV 1024       // v dim
#define KK 4          // top-k
#define TILE 64
#define NTILE_MAX (TT*KK/TILE + EE)   // 1056 upper bound on tiles

// ---------------- ws layout (element offsets, 4B elements) ----------------
#define WS_SELRAW   0                       // 524288 f
#define WS_GATES    524288                  // 65536 f
#define WS_PGATE    589824                  // 65536 f
#define WS_STATS    655360                  // lm_sums 32 f + counts 32 i (memset region)
#define WS_LMSUMS   655360                  // 32 f
#define WS_COUNTS   655392                  // 32 i
#define WS_OFFSETS  655424                  // 33 i
#define WS_CURSORS  655457                  // 32 i
#define WS_NTILES   655489                  // 1 i
#define WS_TMAPE    655490                  // 1056 i
#define WS_TMAPT    656546                  // 1056 i
#define WS_IDXS     657602                  // 65536 i
#define WS_PERM     723138                  // 65536 i
// total ~788674 elems = 3.16 MB

// ---------------------------- router: sel_raw = X * Wsel^T ----------------
__global__ __launch_bounds__(256) void k_router(const float* __restrict__ x,
                                                const float* __restrict__ sel,
                                                float* __restrict__ sel_raw) {
    __shared__ float xs[64][68];   // [token][d-chunk] padded
    __shared__ float ss[32][68];   // [expert][d-chunk] padded
    const int tid = threadIdx.x;
    const int t0 = blockIdx.x * 64;
    const int el = tid & 31;       // expert
    const int tg = tid >> 5;       // token group (8 tokens)
    float acc[8];
#pragma unroll
    for (int i = 0; i < 8; i++) acc[i] = 0.f;

    for (int dc = 0; dc < DD; dc += 64) {
#pragma unroll
        for (int i = 0; i < 4; i++) {            // stage x tile 64x64
            int q = tid + 256 * i;
            int r = q >> 4, c4 = q & 15;
            float4 v = *(const float4*)&x[(size_t)(t0 + r) * DD + dc + c4 * 4];
            *(float4*)&xs[r][c4 * 4] = v;
        }
#pragma unroll
        for (int i = 0; i < 2; i++) {            // stage sel tile 32x64
            int q = tid + 256 * i;
            int e = q >> 4, c4 = q & 15;
            float4 v = *(const float4*)&sel[(size_t)e * DD + dc + c4 * 4];
            *(float4*)&ss[e][c4 * 4] = v;
        }
        __syncthreads();
#pragma unroll
        for (int d4 = 0; d4 < 16; d4++) {
            float4 sv = *(const float4*)&ss[el][d4 * 4];
#pragma unroll
            for (int i = 0; i < 8; i++) {
                float4 xv = *(const float4*)&xs[tg * 8 + i][d4 * 4];
                acc[i] += xv.x * sv.x + xv.y * sv.y + xv.z * sv.z + xv.w * sv.w;
            }
        }
        __syncthreads();
    }
#pragma unroll
    for (int i = 0; i < 8; i++)
        sel_raw[(size_t)(t0 + tg * 8 + i) * EE + el] = acc[i];
}

// ------------- per-token: lse, sigmoid, top-4, counts, lm partials --------
__global__ __launch_bounds__(256) void k_token(const float* __restrict__ sel_raw,
                                               float* __restrict__ gates,
                                               int* __restrict__ idxs,
                                               float* __restrict__ lm_sums,
                                               int* __restrict__ counts) {
    const int t = blockIdx.x * 256 + threadIdx.x;
    float v[32];
#pragma unroll
    for (int j = 0; j < 8; j++) {
        float4 q = *(const float4*)&sel_raw[(size_t)t * EE + j * 4];
        v[j * 4 + 0] = q.x; v[j * 4 + 1] = q.y; v[j * 4 + 2] = q.z; v[j * 4 + 3] = q.w;
    }
    float m = v[0];
#pragma unroll
    for (int e = 1; e < 32; e++) m = fmaxf(m, v[e]);
    float s = 0.f;
#pragma unroll
    for (int e = 0; e < 32; e++) s += expf(v[e] - m);
    const float lse = logf(s) + m;

    // sigmoid values (top-k performed on sigmoid to exactly match ref tie rules)
    float sg[32];
#pragma unroll
    for (int e = 0; e < 32; e++) sg[e] = 1.f / (1.f + expf(-v[e]));

    unsigned taken = 0u;
#pragma unroll
    for (int k = 0; k < KK; k++) {
        float best = -1.f; int bi = 0;
#pragma unroll
        for (int e = 0; e < 32; e++) {
            bool free_e = !((taken >> e) & 1u);
            if (free_e && sg[e] > best) { best = sg[e]; bi = e; }
        }
        taken |= 1u << bi;
        gates[t * KK + k] = best;
        idxs[t * KK + k] = bi;
        atomicAdd(&counts[bi], 1);
    }

    // lm partial sums: p = exp(raw - lse), reduced across the wave
#pragma unroll
    for (int e = 0; e < 32; e++) {
        float pv = expf(v[e] - lse);
#pragma unroll
        for (int o = 32; o >= 1; o >>= 1) pv += __shfl_xor(pv, o, 64);
        if ((threadIdx.x & 63) == 0) atomicAdd(&lm_sums[e], pv);
    }
}

// ------------- tiny: scan counts, build tile map, reg_loss ----------------
__global__ void k_scan(const int* __restrict__ counts, int* __restrict__ offsets,
                       int* __restrict__ cursors, int* __restrict__ tmape,
                       int* __restrict__ tmapt, int* __restrict__ ntiles,
                       const float* __restrict__ lm_sums, float* __restrict__ out_reg) {
    if (threadIdx.x == 0) {
        int off = 0;
        for (int e = 0; e < EE; e++) {
            offsets[e] = off; cursors[e] = off; off += counts[e];
        }
        offsets[EE] = off;
        int nt = 0;
        for (int e = 0; e < EE; e++) {
            int c = counts[e];
            int n = (c + TILE - 1) / TILE;
            for (int j = 0; j < n; j++) { tmape[nt] = e; tmapt[nt] = j; nt++; }
        }
        ntiles[0] = nt;
        // reg_loss = sum_e p_e * log(p_e),  p_e = S_e / T
        float reg = 0.f;
        const float invT = 1.f / (float)TT;
        for (int e = 0; e < EE; e++) {
            float pe = lm_sums[e] * invT;
            reg += pe * logf(pe);
        }
        out_reg[0] = reg;
    }
}

// ------------- scatter token ids into per-expert buckets ------------------
__global__ __launch_bounds__(256) void k_scatter(const int* __restrict__ idxs,
                                                 const float* __restrict__ gates,
                                                 int* __restrict__ cursors,
                                                 int* __restrict__ perm,
                                                 float* __restrict__ pgate) {
    const int t = blockIdx.x * 256 + threadIdx.x;
#pragma unroll
    for (int k = 0; k < KK; k++) {
        int e = idxs[t * KK + k];
        int pos = atomicAdd(&cursors[e], 1);
        perm[pos] = t;
        pgate[pos] = gates[t * KK + k];
    }
}

// ------------- bucketed expert GEMM chain ---------------------------------
struct P1 { float xs[64][68]; float ks[64][128]; };
union ULDS { P1 p1; float hs[64][128]; };

__global__ __launch_bounds__(256) void k_expert(const float* __restrict__ x,
                                                const float* __restrict__ keys,
                                                const float* __restrict__ values,
                                                const int* __restrict__ perm,
                                                const float* __restrict__ pgate,
                                                const int* __restrict__ offsets,
                                                const int* __restrict__ counts,
                                                const int* __restrict__ tmape,
                                                const int* __restrict__ tmapt,
                                                const int* __restrict__ ntiles,
                                                float* __restrict__ out) {
    __shared__ ULDS u;
    __shared__ float gl[64];
    __shared__ int tl[64];

    const int bid = blockIdx.x;
    if (bid >= ntiles[0]) return;
    const int e = tmape[bid];
    const int tile = tmapt[bid];
    const int base = offsets[e] + tile * TILE;
    const int nr = min(TILE, offsets[e] + counts[e] - base);
    const int tid = threadIdx.x;

    if (tid < 64) {
        int tok = 0; float g = 0.f;
        if (tid < nr) { tok = perm[base + tid]; g = pgate[base + tid]; }
        tl[tid] = tok; gl[tid] = g;
    }
    __syncthreads();

    const int fg = tid & 31, tg = tid >> 5;
    // hoist token row ids for staging
    int rr[4]; size_t xrow[4];
#pragma unroll
    for (int i = 0; i < 4; i++) {
        int q = tid + 256 * i;
        rr[i] = q >> 4;
        xrow[i] = (size_t)tl[rr[i]] * DD + (q & 15) * 4;
    }

    float acc[4][8];
#pragma unroll
    for (int mm = 0; mm < 4; mm++)
#pragma unroll
        for (int i = 0; i < 8; i++) acc[mm][i] = 0.f;

    // ---- phase 1: H[64][128] = relu(Xg * keys[e]) * gate ----
    for (int dc = 0; dc < DD; dc += 64) {
#pragma unroll
        for (int i = 0; i < 4; i++) {            // stage x 64x64 (gathered rows)
            int q = tid + 256 * i;
            float4 v = *(const float4*)&x[xrow[i] + dc];
            *(float4*)&u.p1.xs[rr[i]][(q & 15) * 4] = v;
        }
#pragma unroll
        for (int i = 0; i < 8; i++) {            // stage keys 64x128
            int q = tid + 256 * i;
            int d = q >> 5, f4 = q & 31;
            float4 v = *(const float4*)&keys[((size_t)e * DD + dc + d) * ESS + f4 * 4];
            *(float4*)&u.p1.ks[d][f4 * 4] = v;
        }
        __syncthreads();
        for (int d4 = 0; d4 < 16; d4++) {
            float kvf[4][4], xvf[8][4];
#pragma unroll
            for (int jj = 0; jj < 4; jj++) {
                float4 kq = *(const float4*)&u.p1.ks[d4 * 4 + jj][fg * 4];
                kvf[jj][0] = kq.x; kvf[jj][1] = kq.y; kvf[jj][2] = kq.z; kvf[jj][3] = kq.w;
            }
#pragma unroll
            for (int i = 0; i < 8; i++) {
                float4 xq = *(const float4*)&u.p1.xs[tg * 8 + i][d4 * 4];
                xvf[i][0] = xq.x; xvf[i][1] = xq.y; xvf[i][2] = xq.z; xvf[i][3] = xq.w;
            }
#pragma unroll
            for (int i = 0; i < 8; i++)
#pragma unroll
                for (int mm = 0; mm < 4; mm++)
                    acc[mm][i] += xvf[i][0] * kvf[0][mm] + xvf[i][1] * kvf[1][mm]
                                + xvf[i][2] * kvf[2][mm] + xvf[i][3] * kvf[3][mm];
        }
        __syncthreads();
    }

    // relu * gate -> H in LDS (aliases phase-1 buffers; barrier above protects)
#pragma unroll
    for (int i = 0; i < 8; i++) {
        int t = tg * 8 + i;
        float g = gl[t];
        float4 h;
        h.x = fmaxf(acc[0][i], 0.f) * g;
        h.y = fmaxf(acc[1][i], 0.f) * g;
        h.z = fmaxf(acc[2][i], 0.f) * g;
        h.w = fmaxf(acc[3][i], 0.f) * g;
        *(float4*)&u.hs[t][fg * 4] = h;
    }
    __syncthreads();

    // ---- phase 2: OUT[64][1024] = H * values[e], atomic scatter ----
    const int vl = tid & 63, tg2 = tid >> 6;
    for (int vc = 0; vc < VV; vc += 256) {
        float acc2[4][16];
#pragma unroll
        for (int vi = 0; vi < 4; vi++)
#pragma unroll
            for (int tt = 0; tt < 16; tt++) acc2[vi][tt] = 0.f;

        for (int g4 = 0; g4 < 32; g4++) {
            float vals[4][4];
#pragma unroll
            for (int jf = 0; jf < 4; jf++)
#pragma unroll
                for (int vi = 0; vi < 4; vi++)
                    vals[jf][vi] = values[((size_t)e * ESS + g4 * 4 + jf) * VV + vc + vi * 64 + vl];
#pragma unroll
            for (int tt = 0; tt < 16; tt++) {
                float4 hq = *(const float4*)&u.hs[tg2 * 16 + tt][g4 * 4];
#pragma unroll
                for (int vi = 0; vi < 4; vi++)
                    acc2[vi][tt] += hq.x * vals[0][vi] + hq.y * vals[1][vi]
                                  + hq.z * vals[2][vi] + hq.w * vals[3][vi];
            }
        }
#pragma unroll
        for (int tt = 0; tt < 16; tt++) {
            int t = tg2 * 16 + tt;
            if (t < nr) {
                size_t ob = (size_t)tl[t] * VV + vc + vl;
#pragma unroll
                for (int vi = 0; vi < 4; vi++)
                    atomicAdd(&out[ob + (size_t)vi * 64], acc2[vi][tt]);
            }
        }
    }
}

// --------------------------------------------------------------------------
extern "C" void kernel_launch(void* const* d_in, const int* in_sizes, int n_in,
                              void* d_out, int out_size, void* d_ws, size_t ws_size,
                              hipStream_t stream) {
    const float* x      = (const float*)d_in[0];
    const float* keys   = (const float*)d_in[1];
    const float* values = (const float*)d_in[2];
    const float* esel   = (const float*)d_in[3];
    float* out = (float*)d_out;

    float* wsf = (float*)d_ws;
    int*   wsi = (int*)d_ws;

    float* sel_raw = wsf + WS_SELRAW;
    float* gates   = wsf + WS_GATES;
    float* pgate   = wsf + WS_PGATE;
    float* lm_sums = wsf + WS_LMSUMS;
    int*   counts  = wsi + WS_COUNTS;
    int*   offsets = wsi + WS_OFFSETS;
    int*   cursors = wsi + WS_CURSORS;
    int*   ntiles  = wsi + WS_NTILES;
    int*   tmape   = wsi + WS_TMAPE;
    int*   tmapt   = wsi + WS_TMAPT;
    int*   idxs    = wsi + WS_IDXS;
    int*   perm    = wsi + WS_PERM;

    // zero output accumulator + small stats region (every call; harness doesn't re-poison)
    hipMemsetAsync(d_out, 0, (size_t)TT * VV * sizeof(float), stream);
    hipMemsetAsync(wsf + WS_STATS, 0, 64 * sizeof(float), stream);

    k_router<<<TT / 64, 256, 0, stream>>>(x, esel, sel_raw);
    k_token<<<TT / 256, 256, 0, stream>>>(sel_raw, gates, idxs, lm_sums, counts);
    k_scan<<<1, 64, 0, stream>>>(counts, offsets, cursors, tmape, tmapt, ntiles,
                                 lm_sums, out + (size_t)TT * VV);
    k_scatter<<<TT / 256, 256, 0, stream>>>(idxs, gates, cursors, perm, pgate);
    k_expert<<<NTILE_MAX, 256, 0, stream>>>(x, keys, values, perm, pgate,
                                            offsets, counts, tmape, tmapt, ntiles, out);
}

// Round 2
// 614.040 us; speedup vs baseline: 2.1008x; 2.1008x over previous
//
#include <hip/hip_runtime.h>

typedef unsigned int uint;
typedef unsigned short ushort;

#define TT 16384      // tokens = B*S
#define DD 1024       // d_model
#define EE 32         // experts
#define ESS 128       // expert size
#define VV 1024       // v dim
#define KK 4          // top-k
#define TILE 64
#define NTILE_MAX (TT*KK/TILE + EE)   // 1056 upper bound on tiles

typedef __attribute__((ext_vector_type(8))) short bf16x8;   // 8 bf16 = 4 VGPR (guide §3)
typedef __attribute__((ext_vector_type(4))) float f32x4;

// ---------------- ws layout (offsets in 4B units) ----------------
#define WS_SELRAW   0                       // 524288 f
#define WS_GATES    524288                  // 65536 f
#define WS_PGATE    589824                  // 65536 f
#define WS_STATS    655360                  // lm_sums 32 f + counts 32 i (memset region)
#define WS_LMSUMS   655360
#define WS_COUNTS   655392
#define WS_OFFSETS  655424                  // 33 i
#define WS_CURSORS  655457                  // 32 i
#define WS_NTILES   655489                  // 1 i
#define WS_TMAPE    655490                  // 1056 i
#define WS_TMAPT    656546                  // 1056 i
#define WS_IDXS     657602                  // 65536 i
#define WS_PERM     723138                  // 65536 i
// bf16 buffers (16B-aligned starts, sizes in uint units = 2 bf16 each)
#define WS_XB       788736                  // x bf16 [16384][1024] -> 8388608 uints
#define WS_KT       9177344                 // keys^T bf16 [32][128][1024] -> 2097152 uints
#define WS_VT       11274496                // values^T bf16 [32][1024][128] -> 2097152 uints
// total 13371648 uints = 53.5 MB of d_ws

// fp32 -> bf16 RNE
__device__ __forceinline__ ushort f2b(float f) {
    uint u = __builtin_bit_cast(uint, f);
    u = (u + 0x7fffu + ((u >> 16) & 1u)) >> 16;
    return (ushort)u;
}
__device__ __forceinline__ uint bpack(float lo, float hi) {
    return (uint)f2b(lo) | ((uint)f2b(hi) << 16);
}

// ---------------- bf16 conversion: x ----------------
__global__ __launch_bounds__(256) void k_cvt_x(const float* __restrict__ x,
                                               uint* __restrict__ xb) {
    const size_t i = ((size_t)blockIdx.x * 256 + threadIdx.x) * 8;
    float4 a = *(const float4*)&x[i];
    float4 b = *(const float4*)&x[i + 4];
    uint4 r;
    r.x = bpack(a.x, a.y); r.y = bpack(a.z, a.w);
    r.z = bpack(b.x, b.y); r.w = bpack(b.z, b.w);
    *(uint4*)&xb[i / 2] = r;
}

// ------------- per-expert transpose [R][C] f32 -> [C][R] bf16 -------------
__global__ __launch_bounds__(256) void k_tr(const float* __restrict__ in,
                                            ushort* __restrict__ outp,
                                            int R, int C) {
    __shared__ float t[32][33];
    const int e = blockIdx.z;
    const float* src = in + (size_t)e * R * C;
    ushort* dst = outp + (size_t)e * R * C;
    const int r0 = blockIdx.x * 32, c0 = blockIdx.y * 32;
    const int tr = threadIdx.x >> 3, tc4 = (threadIdx.x & 7) * 4;
    float4 v = *(const float4*)&src[(size_t)(r0 + tr) * C + c0 + tc4];
    t[tr][tc4] = v.x; t[tr][tc4 + 1] = v.y; t[tr][tc4 + 2] = v.z; t[tr][tc4 + 3] = v.w;
    __syncthreads();
    ushort4 o;
    o.x = f2b(t[tc4 + 0][tr]); o.y = f2b(t[tc4 + 1][tr]);
    o.z = f2b(t[tc4 + 2][tr]); o.w = f2b(t[tc4 + 3][tr]);
    *(ushort4*)&dst[(size_t)(c0 + tr) * R + r0 + tc4] = o;
}

// ---------------------------- router: sel_raw = X * Wsel^T (fp32!) --------
// fp32 on purpose: bf16 logits flip ~1% of top-4 picks -> O(1) output errors.
__global__ __launch_bounds__(256) void k_router(const float* __restrict__ x,
                                                const float* __restrict__ sel,
                                                float* __restrict__ sel_raw) {
    __shared__ float xs[64][68];
    __shared__ float ss[32][68];
    const int tid = threadIdx.x;
    const int t0 = blockIdx.x * 64;
    const int el = tid & 31;
    const int tg = tid >> 5;
    float acc[8];
#pragma unroll
    for (int i = 0; i < 8; i++) acc[i] = 0.f;

    for (int dc = 0; dc < DD; dc += 64) {
#pragma unroll
        for (int i = 0; i < 4; i++) {
            int q = tid + 256 * i;
            int r = q >> 4, c4 = q & 15;
            float4 v = *(const float4*)&x[(size_t)(t0 + r) * DD + dc + c4 * 4];
            *(float4*)&xs[r][c4 * 4] = v;
        }
#pragma unroll
        for (int i = 0; i < 2; i++) {
            int q = tid + 256 * i;
            int e = q >> 4, c4 = q & 15;
            float4 v = *(const float4*)&sel[(size_t)e * DD + dc + c4 * 4];
            *(float4*)&ss[e][c4 * 4] = v;
        }
        __syncthreads();
#pragma unroll
        for (int d4 = 0; d4 < 16; d4++) {
            float4 sv = *(const float4*)&ss[el][d4 * 4];
#pragma unroll
            for (int i = 0; i < 8; i++) {
                float4 xv = *(const float4*)&xs[tg * 8 + i][d4 * 4];
                acc[i] += xv.x * sv.x + xv.y * sv.y + xv.z * sv.z + xv.w * sv.w;
            }
        }
        __syncthreads();
    }
#pragma unroll
    for (int i = 0; i < 8; i++)
        sel_raw[(size_t)(t0 + tg * 8 + i) * EE + el] = acc[i];
}

// ------------- per-token: lse, sigmoid, top-4, block-agg counts/lm --------
__global__ __launch_bounds__(256) void k_token(const float* __restrict__ sel_raw,
                                               float* __restrict__ gates,
                                               int* __restrict__ idxs,
                                               float* __restrict__ lm_sums,
                                               int* __restrict__ counts) {
    __shared__ int hist[EE];
    __shared__ float lmh[EE];
    const int tid = threadIdx.x;
    if (tid < EE) { hist[tid] = 0; lmh[tid] = 0.f; }
    __syncthreads();

    const int t = blockIdx.x * 256 + tid;
    float v[32];
#pragma unroll
    for (int j = 0; j < 8; j++) {
        float4 q = *(const float4*)&sel_raw[(size_t)t * EE + j * 4];
        v[j * 4 + 0] = q.x; v[j * 4 + 1] = q.y; v[j * 4 + 2] = q.z; v[j * 4 + 3] = q.w;
    }
    float m = v[0];
#pragma unroll
    for (int e = 1; e < 32; e++) m = fmaxf(m, v[e]);
    float s = 0.f;
#pragma unroll
    for (int e = 0; e < 32; e++) s += expf(v[e] - m);
    const float lse = logf(s) + m;

    float sg[32];
#pragma unroll
    for (int e = 0; e < 32; e++) sg[e] = 1.f / (1.f + expf(-v[e]));

    unsigned taken = 0u;
#pragma unroll
    for (int k = 0; k < KK; k++) {
        float best = -1.f; int bi = 0;
#pragma unroll
        for (int e = 0; e < 32; e++) {
            bool free_e = !((taken >> e) & 1u);
            if (free_e && sg[e] > best) { best = sg[e]; bi = e; }
        }
        taken |= 1u << bi;
        gates[t * KK + k] = best;
        idxs[t * KK + k] = bi;
        atomicAdd(&hist[bi], 1);
    }

#pragma unroll
    for (int e = 0; e < 32; e++) {
        float pv = expf(v[e] - lse);
#pragma unroll
        for (int o = 32; o >= 1; o >>= 1) pv += __shfl_xor(pv, o, 64);
        if ((tid & 63) == 0) atomicAdd(&lmh[e], pv);
    }
    __syncthreads();
    if (tid < EE) {
        atomicAdd(&counts[tid], hist[tid]);
        atomicAdd(&lm_sums[tid], lmh[tid]);
    }
}

// ------------- wave-parallel: scan counts, tile map, reg_loss -------------
__global__ void k_scan(const int* __restrict__ counts, int* __restrict__ offsets,
                       int* __restrict__ cursors, int* __restrict__ tmape,
                       int* __restrict__ tmapt, int* __restrict__ ntiles,
                       const float* __restrict__ lm_sums, float* __restrict__ out_reg) {
    const int lane = threadIdx.x;          // one wave of 64
    int c = (lane < EE) ? counts[lane] : 0;
    int p = c;
#pragma unroll
    for (int o = 1; o < 32; o <<= 1) { int u = __shfl_up(p, o, 64); if (lane >= o) p += u; }
    const int off = p - c;                 // exclusive prefix
    if (lane < EE) { offsets[lane] = off; cursors[lane] = off; }
    if (lane == EE - 1) offsets[EE] = p;

    int nt = (c + TILE - 1) / TILE;
    int q = nt;
#pragma unroll
    for (int o = 1; o < 32; o <<= 1) { int u = __shfl_up(q, o, 64); if (lane >= o) q += u; }
    const int tb = q - nt;
    if (lane < EE)
        for (int j = 0; j < nt; j++) { tmape[tb + j] = lane; tmapt[tb + j] = j; }
    if (lane == EE - 1) ntiles[0] = q;

    float rv = 0.f;
    if (lane < EE) {
        float pe = lm_sums[lane] * (1.f / (float)TT);
        rv = pe * logf(pe);
    }
#pragma unroll
    for (int o = 16; o >= 1; o >>= 1) rv += __shfl_down(rv, o, 64);
    if (lane == 0) out_reg[0] = rv;
}

// ------------- scatter token ids into per-expert buckets (block-agg) ------
__global__ __launch_bounds__(256) void k_scatter(const int* __restrict__ idxs,
                                                 const float* __restrict__ gates,
                                                 int* __restrict__ cursors,
                                                 int* __restrict__ perm,
                                                 float* __restrict__ pgate) {
    __shared__ int lh[EE];
    __shared__ int lbase[EE];
    const int tid = threadIdx.x;
    if (tid < EE) lh[tid] = 0;
    __syncthreads();
    const int t = blockIdx.x * 256 + tid;
    int ee[KK], rk[KK];
#pragma unroll
    for (int k = 0; k < KK; k++) {
        ee[k] = idxs[t * KK + k];
        rk[k] = atomicAdd(&lh[ee[k]], 1);
    }
    __syncthreads();
    if (tid < EE) lbase[tid] = atomicAdd(&cursors[tid], lh[tid]);
    __syncthreads();
#pragma unroll
    for (int k = 0; k < KK; k++) {
        int pos = lbase[ee[k]] + rk[k];
        perm[pos] = t;
        pgate[pos] = gates[t * KK + k];
    }
}

// ------------- bucketed expert chain: bf16 MFMA -------------
// phase 1: H[64][128] = relu(Xg[64][1024] * K[1024][128]) * gate   (32 ksteps x 8 nfrags)
// phase 2: OUT[64][1024] += H[64][128] * V[128][1024]              (4 chunks x 4 ksteps x 16 nfrags)
// Fragments (guide §3, m89/m91-verified family): A row=lane&15, k=(lane>>4)*8+[0..7];
// B col=lane&15, same k; C/D row=(lane>>4)*4+reg, col=lane&15.
// All A/B loads are contiguous 16B per lane straight from global (weights L2-resident).
__global__ __launch_bounds__(256) void k_expert(
    const ushort* __restrict__ xb, const ushort* __restrict__ ktb,
    const ushort* __restrict__ vtb,
    const int* __restrict__ perm, const float* __restrict__ pgate,
    const int* __restrict__ offsets, const int* __restrict__ counts,
    const int* __restrict__ tmape, const int* __restrict__ tmapt,
    const int* __restrict__ ntiles, float* __restrict__ out)
{
    __shared__ ushort hs[4][16][136];   // per-wave H, bf16, +8 pad (2-way-free reads)
    __shared__ float gl[64];
    __shared__ int tl[64];

    const int bid = blockIdx.x;
    if (bid >= ntiles[0]) return;
    const int e = tmape[bid];
    const int base = offsets[e] + tmapt[bid] * TILE;
    const int nr = min(TILE, offsets[e] + counts[e] - base);
    const int tid = threadIdx.x;

    if (tid < 64) {
        int tok = 0; float g = 0.f;
        if (tid < nr) { tok = perm[base + tid]; g = pgate[base + tid]; }
        tl[tid] = tok; gl[tid] = g;
    }
    __syncthreads();

    const int wid = tid >> 6, lane = tid & 63;
    const int lr = lane & 15, lq = lane >> 4;
    const int m0 = wid * 16;             // wave owns 16 token rows

    // ---- phase 1 ----
    const size_t abase = (size_t)tl[m0 + lr] * DD + lq * 8;
    const size_t kb0 = ((size_t)e * ESS + lr) * DD + lq * 8;

    f32x4 acc[8];
#pragma unroll
    for (int nf = 0; nf < 8; nf++) acc[nf] = (f32x4){0.f, 0.f, 0.f, 0.f};

    for (int ks = 0; ks < 32; ks++) {
        bf16x8 a = *(const bf16x8*)(xb + abase + ks * 32);
#pragma unroll
        for (int nf = 0; nf < 8; nf++) {
            bf16x8 b = *(const bf16x8*)(ktb + kb0 + (size_t)nf * (16 * DD) + ks * 32);
            acc[nf] = __builtin_amdgcn_mfma_f32_16x16x32_bf16(a, b, acc[nf], 0, 0, 0);
        }
    }

    // relu*gate -> bf16 H in per-wave LDS (no cross-wave sharing -> no barrier)
    float g4[4];
#pragma unroll
    for (int r = 0; r < 4; r++) g4[r] = gl[m0 + lq * 4 + r];
#pragma unroll
    for (int nf = 0; nf < 8; nf++)
#pragma unroll
        for (int r = 0; r < 4; r++) {
            float h = fmaxf(acc[nf][r], 0.f) * g4[r];
            hs[wid][lq * 4 + r][nf * 16 + lr] = f2b(h);
        }

    int trow[4]; bool vrow[4];
#pragma unroll
    for (int r = 0; r < 4; r++) {
        int row = m0 + lq * 4 + r;
        trow[r] = tl[row]; vrow[r] = (row < nr);
    }

    // ---- phase 2 ----
    const size_t vb0 = ((size_t)e * VV + lr) * ESS + lq * 8;
    for (int ch = 0; ch < 4; ch++) {
        f32x4 acc2[16];
#pragma unroll
        for (int nf = 0; nf < 16; nf++) acc2[nf] = (f32x4){0.f, 0.f, 0.f, 0.f};
#pragma unroll
        for (int ks = 0; ks < 4; ks++) {
            bf16x8 a = *(const bf16x8*)&hs[wid][lr][ks * 32 + lq * 8];
#pragma unroll
            for (int nf = 0; nf < 16; nf++) {
                bf16x8 b = *(const bf16x8*)(vtb + vb0 + (size_t)(ch * 256 + nf * 16) * ESS + ks * 32);
                acc2[nf] = __builtin_amdgcn_mfma_f32_16x16x32_bf16(a, b, acc2[nf], 0, 0, 0);
            }
        }
#pragma unroll
        for (int nf = 0; nf < 16; nf++)
#pragma unroll
            for (int r = 0; r < 4; r++)
                if (vrow[r])
                    atomicAdd(&out[(size_t)trow[r] * VV + ch * 256 + nf * 16 + lr],
                              acc2[nf][r]);
    }
}

// --------------------------------------------------------------------------
extern "C" void kernel_launch(void* const* d_in, const int* in_sizes, int n_in,
                              void* d_out, int out_size, void* d_ws, size_t ws_size,
                              hipStream_t stream) {
    const float* x      = (const float*)d_in[0];
    const float* keys   = (const float*)d_in[1];
    const float* values = (const float*)d_in[2];
    const float* esel   = (const float*)d_in[3];
    float* out = (float*)d_out;

    float* wsf = (float*)d_ws;
    int*   wsi = (int*)d_ws;

    float* sel_raw = wsf + WS_SELRAW;
    float* gates   = wsf + WS_GATES;
    float* pgate   = wsf + WS_PGATE;
    float* lm_sums = wsf + WS_LMSUMS;
    int*   counts  = wsi + WS_COUNTS;
    int*   offsets = wsi + WS_OFFSETS;
    int*   cursors = wsi + WS_CURSORS;
    int*   ntiles  = wsi + WS_NTILES;
    int*   tmape   = wsi + WS_TMAPE;
    int*   tmapt   = wsi + WS_TMAPT;
    int*   idxs    = wsi + WS_IDXS;
    int*   perm    = wsi + WS_PERM;
    uint*   xbu = (uint*)(wsf + WS_XB);
    ushort* xb  = (ushort*)xbu;
    ushort* ktb = (ushort*)(wsf + WS_KT);
    ushort* vtb = (ushort*)(wsf + WS_VT);

    hipMemsetAsync(d_out, 0, (size_t)TT * VV * sizeof(float), stream);
    hipMemsetAsync(wsf + WS_STATS, 0, 64 * sizeof(float), stream);

    k_cvt_x<<<TT * DD / (256 * 8), 256, 0, stream>>>(x, xbu);
    k_tr<<<dim3(DD / 32, ESS / 32, EE), 256, 0, stream>>>(keys, ktb, DD, ESS);
    k_tr<<<dim3(ESS / 32, VV / 32, EE), 256, 0, stream>>>(values, vtb, ESS, VV);

    k_router<<<TT / 64, 256, 0, stream>>>(x, esel, sel_raw);
    k_token<<<TT / 256, 256, 0, stream>>>(sel_raw, gates, idxs, lm_sums, counts);
    k_scan<<<1, 64, 0, stream>>>(counts, offsets, cursors, tmape, tmapt, ntiles,
                                 lm_sums, out + (size_t)TT * VV);
    k_scatter<<<TT / 256, 256, 0, stream>>>(idxs, gates, cursors, perm, pgate);
    k_expert<<<NTILE_MAX, 256, 0, stream>>>(xb, ktb, vtb, perm, pgate,
                                            offsets, counts, tmape, tmapt, ntiles, out);
}

// Round 3
// 434.262 us; speedup vs baseline: 2.9704x; 1.4140x over previous
//
#include <hip/hip_runtime.h>

typedef unsigned int uint;
typedef unsigned short ushort;

#define TT 16384      // tokens = B*S
#define DD 1024       // d_model
#define EE 32         // experts
#define ESS 128       // expert size
#define VV 1024       // v dim
#define KK 4          // top-k
#define TILE 64
#define NTILE_MAX 1056   // 16384*4/64 + 32 ; == 8*132 (XCD-swizzle friendly)

typedef __attribute__((ext_vector_type(8))) short bf16x8;   // 8 bf16 = 4 VGPR
typedef __attribute__((ext_vector_type(16))) float f32x16;

// ---------------- ws layout (offsets in 4B units) ----------------
#define WS_SELRAW   0                       // 524288 f
#define WS_GATES    524288                  // 65536 f
#define WS_PGATE    589824                  // 65536 f
#define WS_STATS    655360                  // lm_sums 32 f + counts 32 i (memset region)
#define WS_LMSUMS   655360
#define WS_COUNTS   655392
#define WS_OFFSETS  655424                  // 33 i
#define WS_CURSORS  655457                  // 32 i
#define WS_NTILES   655489                  // 1 i
#define WS_TMAPE    655490                  // 1056 i
#define WS_TMAPT    656546                  // 1056 i
#define WS_IDXS     657602                  // 65536 i
#define WS_PERM     723138                  // 65536 i
// bf16 buffers (16B-aligned starts, sizes in uint units)
#define WS_XB       788736                  // x bf16 [16384][1024] -> 8388608 uints
#define WS_KF       9177344                 // keys frag-major [32][64][4][64][8] -> 2097152 uints
#define WS_VF       11274496                // values frag-major [32][32][8][64][8] -> 2097152 uints

// fp32 -> bf16 RNE
__device__ __forceinline__ ushort f2b(float f) {
    uint u = __builtin_bit_cast(uint, f);
    u = (u + 0x7fffu + ((u >> 16) & 1u)) >> 16;
    return (ushort)u;
}
__device__ __forceinline__ uint bpack(float lo, float hi) {
    return (uint)f2b(lo) | ((uint)f2b(hi) << 16);
}

// ---------------- bf16 conversion: x ----------------
__global__ __launch_bounds__(256) void k_cvt_x(const float* __restrict__ x,
                                               uint* __restrict__ xb) {
    const size_t i = ((size_t)blockIdx.x * 256 + threadIdx.x) * 8;
    float4 a = *(const float4*)&x[i];
    float4 b = *(const float4*)&x[i + 4];
    uint4 r;
    r.x = bpack(a.x, a.y); r.y = bpack(a.z, a.w);
    r.z = bpack(b.x, b.y); r.w = bpack(b.z, b.w);
    *(uint4*)&xb[i / 2] = r;
}

// ------------- keys -> B-fragment-major bf16 -------------
// kfb[e][ks=0..63][nf=0..3][lane=0..63][j=0..7] = keys[e][ks*16+(lane>>5)*8+j][nf*32+(lane&31)]
__global__ __launch_bounds__(256) void k_prep_k(const float* __restrict__ keys,
                                                ushort* __restrict__ kfb) {
    const int e = blockIdx.x >> 6, ks = blockIdx.x & 63;
    const int nf = threadIdx.x >> 6, l = threadIdx.x & 63;
    const int f = nf * 32 + (l & 31);
    const int d0 = ks * 16 + (l >> 5) * 8;
    const float* src = keys + ((size_t)e * DD + d0) * ESS + f;
    float v[8];
#pragma unroll
    for (int j = 0; j < 8; j++) v[j] = src[(size_t)j * ESS];
    uint4 r = { bpack(v[0], v[1]), bpack(v[2], v[3]), bpack(v[4], v[5]), bpack(v[6], v[7]) };
    const size_t off = (((size_t)e * 64 + ks) * 4 + nf) * 512 + l * 8;
    *(uint4*)(kfb + off) = r;
}

// ------------- values -> B-fragment-major bf16 -------------
// vfb[e][nv=0..31][ks=0..7][lane][j] = values[e][ks*16+(lane>>5)*8+j][nv*32+(lane&31)]
__global__ __launch_bounds__(512) void k_prep_v(const float* __restrict__ values,
                                                ushort* __restrict__ vfb) {
    const int e = blockIdx.x >> 5, nv = blockIdx.x & 31;
    const int ks = threadIdx.x >> 6, l = threadIdx.x & 63;
    const int v0 = nv * 32 + (l & 31);
    const int f0 = ks * 16 + (l >> 5) * 8;
    const float* src = values + ((size_t)e * ESS + f0) * VV + v0;
    float v[8];
#pragma unroll
    for (int j = 0; j < 8; j++) v[j] = src[(size_t)j * VV];
    uint4 r = { bpack(v[0], v[1]), bpack(v[2], v[3]), bpack(v[4], v[5]), bpack(v[6], v[7]) };
    const size_t off = (((size_t)e * 32 + nv) * 8 + ks) * 512 + l * 8;
    *(uint4*)(vfb + off) = r;
}

// ---------------------------- router: sel_raw = X * Wsel^T (fp32!) --------
// fp32 on purpose: bf16 logits flip ~1% of top-4 picks -> O(1) output errors.
__global__ __launch_bounds__(256) void k_router(const float* __restrict__ x,
                                                const float* __restrict__ sel,
                                                float* __restrict__ sel_raw) {
    __shared__ float xs[64][68];
    __shared__ float ss[32][68];
    const int tid = threadIdx.x;
    const int t0 = blockIdx.x * 64;
    const int el = tid & 31;
    const int tg = tid >> 5;
    float acc[8];
#pragma unroll
    for (int i = 0; i < 8; i++) acc[i] = 0.f;

    for (int dc = 0; dc < DD; dc += 64) {
#pragma unroll
        for (int i = 0; i < 4; i++) {
            int q = tid + 256 * i;
            int r = q >> 4, c4 = q & 15;
            float4 v = *(const float4*)&x[(size_t)(t0 + r) * DD + dc + c4 * 4];
            *(float4*)&xs[r][c4 * 4] = v;
        }
#pragma unroll
        for (int i = 0; i < 2; i++) {
            int q = tid + 256 * i;
            int e = q >> 4, c4 = q & 15;
            float4 v = *(const float4*)&sel[(size_t)e * DD + dc + c4 * 4];
            *(float4*)&ss[e][c4 * 4] = v;
        }
        __syncthreads();
#pragma unroll
        for (int d4 = 0; d4 < 16; d4++) {
            float4 sv = *(const float4*)&ss[el][d4 * 4];
#pragma unroll
            for (int i = 0; i < 8; i++) {
                float4 xv = *(const float4*)&xs[tg * 8 + i][d4 * 4];
                acc[i] += xv.x * sv.x + xv.y * sv.y + xv.z * sv.z + xv.w * sv.w;
            }
        }
        __syncthreads();
    }
#pragma unroll
    for (int i = 0; i < 8; i++)
        sel_raw[(size_t)(t0 + tg * 8 + i) * EE + el] = acc[i];
}

// ------------- per-token: lse, sigmoid, top-4, block-agg counts/lm --------
__global__ __launch_bounds__(256) void k_token(const float* __restrict__ sel_raw,
                                               float* __restrict__ gates,
                                               int* __restrict__ idxs,
                                               float* __restrict__ lm_sums,
                                               int* __restrict__ counts) {
    __shared__ int hist[EE];
    __shared__ float lmh[EE];
    const int tid = threadIdx.x;
    if (tid < EE) { hist[tid] = 0; lmh[tid] = 0.f; }
    __syncthreads();

    const int t = blockIdx.x * 256 + tid;
    float v[32];
#pragma unroll
    for (int j = 0; j < 8; j++) {
        float4 q = *(const float4*)&sel_raw[(size_t)t * EE + j * 4];
        v[j * 4 + 0] = q.x; v[j * 4 + 1] = q.y; v[j * 4 + 2] = q.z; v[j * 4 + 3] = q.w;
    }
    float m = v[0];
#pragma unroll
    for (int e = 1; e < 32; e++) m = fmaxf(m, v[e]);
    float s = 0.f;
#pragma unroll
    for (int e = 0; e < 32; e++) s += expf(v[e] - m);
    const float lse = logf(s) + m;

    float sg[32];
#pragma unroll
    for (int e = 0; e < 32; e++) sg[e] = 1.f / (1.f + expf(-v[e]));

    unsigned taken = 0u;
#pragma unroll
    for (int k = 0; k < KK; k++) {
        float best = -1.f; int bi = 0;
#pragma unroll
        for (int e = 0; e < 32; e++) {
            bool free_e = !((taken >> e) & 1u);
            if (free_e && sg[e] > best) { best = sg[e]; bi = e; }
        }
        taken |= 1u << bi;
        gates[t * KK + k] = best;
        idxs[t * KK + k] = bi;
        atomicAdd(&hist[bi], 1);
    }

#pragma unroll
    for (int e = 0; e < 32; e++) {
        float pv = expf(v[e] - lse);
#pragma unroll
        for (int o = 32; o >= 1; o >>= 1) pv += __shfl_xor(pv, o, 64);
        if ((tid & 63) == 0) atomicAdd(&lmh[e], pv);
    }
    __syncthreads();
    if (tid < EE) {
        atomicAdd(&counts[tid], hist[tid]);
        atomicAdd(&lm_sums[tid], lmh[tid]);
    }
}

// ------------- wave-parallel: scan counts, tile map, reg_loss -------------
__global__ void k_scan(const int* __restrict__ counts, int* __restrict__ offsets,
                       int* __restrict__ cursors, int* __restrict__ tmape,
                       int* __restrict__ tmapt, int* __restrict__ ntiles,
                       const float* __restrict__ lm_sums, float* __restrict__ out_reg) {
    const int lane = threadIdx.x;          // one wave of 64
    int c = (lane < EE) ? counts[lane] : 0;
    int p = c;
#pragma unroll
    for (int o = 1; o < 32; o <<= 1) { int u = __shfl_up(p, o, 64); if (lane >= o) p += u; }
    const int off = p - c;                 // exclusive prefix
    if (lane < EE) { offsets[lane] = off; cursors[lane] = off; }
    if (lane == EE - 1) offsets[EE] = p;

    int nt = (c + TILE - 1) / TILE;
    int q = nt;
#pragma unroll
    for (int o = 1; o < 32; o <<= 1) { int u = __shfl_up(q, o, 64); if (lane >= o) q += u; }
    const int tb = q - nt;
    if (lane < EE)
        for (int j = 0; j < nt; j++) { tmape[tb + j] = lane; tmapt[tb + j] = j; }
    if (lane == EE - 1) ntiles[0] = q;

    float rv = 0.f;
    if (lane < EE) {
        float pe = lm_sums[lane] * (1.f / (float)TT);
        rv = pe * logf(pe);
    }
#pragma unroll
    for (int o = 16; o >= 1; o >>= 1) rv += __shfl_down(rv, o, 64);
    if (lane == 0) out_reg[0] = rv;
}

// ------------- scatter token ids into per-expert buckets (block-agg) ------
__global__ __launch_bounds__(256) void k_scatter(const int* __restrict__ idxs,
                                                 const float* __restrict__ gates,
                                                 int* __restrict__ cursors,
                                                 int* __restrict__ perm,
                                                 float* __restrict__ pgate) {
    __shared__ int lh[EE];
    __shared__ int lbase[EE];
    const int tid = threadIdx.x;
    if (tid < EE) lh[tid] = 0;
    __syncthreads();
    const int t = blockIdx.x * 256 + tid;
    int ee[KK], rk[KK];
#pragma unroll
    for (int k = 0; k < KK; k++) {
        ee[k] = idxs[t * KK + k];
        rk[k] = atomicAdd(&lh[ee[k]], 1);
    }
    __syncthreads();
    if (tid < EE) lbase[tid] = atomicAdd(&cursors[tid], lh[tid]);
    __syncthreads();
#pragma unroll
    for (int k = 0; k < KK; k++) {
        int pos = lbase[ee[k]] + rk[k];
        perm[pos] = t;
        pgate[pos] = gates[t * KK + k];
    }
}

// ------------- bucketed expert chain: 32x32x16 bf16 MFMA -------------
// phase 1: H[64][128] = relu(Xg * keys[e]) * gate  (waves 2x2: 32 tok x 64 f each)
// phase 2: OUT[64][1024] += H * values[e]          (waves: 32 tok x 512 v each)
// A (32x32x16): row=lane&31, k=(lane>>5)*8+j.  B: col=lane&31, same k.
// C/D (m74/m101-verified): col=lane&31, row=(reg&3)+8*(reg>>2)+4*(lane>>5).
// B-frags come straight from fragment-major global arrays: contiguous 1KB/wave-load.
__global__ __launch_bounds__(256) void k_expert(
    const ushort* __restrict__ xb, const ushort* __restrict__ kfb,
    const ushort* __restrict__ vfb,
    const int* __restrict__ perm, const float* __restrict__ pgate,
    const int* __restrict__ offsets, const int* __restrict__ counts,
    const int* __restrict__ tmape, const int* __restrict__ tmapt,
    const int* __restrict__ ntiles, float* __restrict__ out)
{
    __shared__ ushort hs[64][128];   // H bf16, XOR-swizzled cols (granule8 ^ row&7)
    __shared__ float gl[64];
    __shared__ int tl[64];

    // bijective XCD swizzle: 1056 = 8*132 -> each XCD gets a contiguous chunk of
    // the expert-major tile list => per-XCD weight working set ~2MB fits its L2.
    const int bid = (blockIdx.x & 7) * 132 + (blockIdx.x >> 3);
    if (bid >= ntiles[0]) return;
    const int e = tmape[bid];
    const int base = offsets[e] + tmapt[bid] * TILE;
    const int nr = min(TILE, offsets[e] + counts[e] - base);
    const int tid = threadIdx.x;

    if (tid < 64) {
        int tok = 0; float g = 0.f;
        if (tid < nr) { tok = perm[base + tid]; g = pgate[base + tid]; }
        tl[tid] = tok; gl[tid] = g;
    }
    __syncthreads();

    const int lane = tid & 63, wid = tid >> 6;
    const int wm = wid >> 1, wn = wid & 1;      // 2x2 wave grid
    const int l31 = lane & 31, l5 = lane >> 5;
    const int trow = wm * 32 + l31;

    // ---- phase 1: acc0/acc1 = Xg(32 rows) * keys cols [wn*64 .. +64) ----
    const size_t arow = (size_t)tl[trow] * DD + l5 * 8;
    const ushort* kb = kfb + ((size_t)e * 256 + wn * 2) * 512 + lane * 8;

    f32x16 acc0, acc1;
#pragma unroll
    for (int r = 0; r < 16; r++) { acc0[r] = 0.f; acc1[r] = 0.f; }

#pragma unroll 8
    for (int ks = 0; ks < 64; ks++) {
        bf16x8 a  = *(const bf16x8*)(xb + arow + (size_t)ks * 16);
        bf16x8 b0 = *(const bf16x8*)(kb + (size_t)ks * 2048);
        bf16x8 b1 = *(const bf16x8*)(kb + (size_t)ks * 2048 + 512);
        acc0 = __builtin_amdgcn_mfma_f32_32x32x16_bf16(a, b0, acc0, 0, 0, 0);
        acc1 = __builtin_amdgcn_mfma_f32_32x32x16_bf16(a, b1, acc1, 0, 0, 0);
    }

    // relu * gate -> swizzled bf16 H in LDS
#pragma unroll
    for (int r = 0; r < 16; r++) {
        int row = (r & 3) + 8 * (r >> 2) + 4 * l5;
        int grow = wm * 32 + row;
        float g = gl[grow];
        int c0 = wn * 64 + l31;
        int c1 = c0 + 32;
        int sw = (grow & 7) << 3;
        hs[grow][c0 ^ sw] = f2b(fmaxf(acc0[r], 0.f) * g);
        hs[grow][c1 ^ sw] = f2b(fmaxf(acc1[r], 0.f) * g);
    }
    __syncthreads();

    // ---- phase 2: A-frags (H) hoisted to regs, B streamed frag-major ----
    bf16x8 af[8];
    const int hr = wm * 32 + l31;
    const int hsw = (hr & 7) << 3;
#pragma unroll
    for (int ks = 0; ks < 8; ks++) {
        int c = ks * 16 + l5 * 8;
        af[ks] = *(const bf16x8*)&hs[hr][c ^ hsw];
    }

    int ptok[16]; bool pv[16];
#pragma unroll
    for (int r = 0; r < 16; r++) {
        int row = wm * 32 + (r & 3) + 8 * (r >> 2) + 4 * l5;
        ptok[r] = tl[row]; pv[r] = (row < nr);
    }

    const ushort* vb = vfb + ((size_t)e * 32 + wn * 16) * 4096 + lane * 8;
    for (int nv = 0; nv < 16; nv++) {
        f32x16 acc;
#pragma unroll
        for (int r = 0; r < 16; r++) acc[r] = 0.f;
#pragma unroll
        for (int ks = 0; ks < 8; ks++) {
            bf16x8 b = *(const bf16x8*)(vb + ((size_t)nv * 8 + ks) * 512);
            acc = __builtin_amdgcn_mfma_f32_32x32x16_bf16(af[ks], b, acc, 0, 0, 0);
        }
        const int colb = wn * 512 + nv * 32 + l31;
#pragma unroll
        for (int r = 0; r < 16; r++)
            if (pv[r])
                atomicAdd(&out[(size_t)ptok[r] * VV + colb], acc[r]);
    }
}

// --------------------------------------------------------------------------
extern "C" void kernel_launch(void* const* d_in, const int* in_sizes, int n_in,
                              void* d_out, int out_size, void* d_ws, size_t ws_size,
                              hipStream_t stream) {
    const float* x      = (const float*)d_in[0];
    const float* keys   = (const float*)d_in[1];
    const float* values = (const float*)d_in[2];
    const float* esel   = (const float*)d_in[3];
    float* out = (float*)d_out;

    float* wsf = (float*)d_ws;
    int*   wsi = (int*)d_ws;

    float* sel_raw = wsf + WS_SELRAW;
    float* gates   = wsf + WS_GATES;
    float* pgate   = wsf + WS_PGATE;
    float* lm_sums = wsf + WS_LMSUMS;
    int*   counts  = wsi + WS_COUNTS;
    int*   offsets = wsi + WS_OFFSETS;
    int*   cursors = wsi + WS_CURSORS;
    int*   ntiles  = wsi + WS_NTILES;
    int*   tmape   = wsi + WS_TMAPE;
    int*   tmapt   = wsi + WS_TMAPT;
    int*   idxs    = wsi + WS_IDXS;
    int*   perm    = wsi + WS_PERM;
    uint*   xbu = (uint*)(wsf + WS_XB);
    ushort* xb  = (ushort*)xbu;
    ushort* kfb = (ushort*)(wsf + WS_KF);
    ushort* vfb = (ushort*)(wsf + WS_VF);

    hipMemsetAsync(d_out, 0, (size_t)TT * VV * sizeof(float), stream);
    hipMemsetAsync(wsf + WS_STATS, 0, 64 * sizeof(float), stream);

    k_cvt_x<<<TT * DD / (256 * 8), 256, 0, stream>>>(x, xbu);
    k_prep_k<<<EE * 64, 256, 0, stream>>>(keys, kfb);
    k_prep_v<<<EE * 32, 512, 0, stream>>>(values, vfb);

    k_router<<<TT / 64, 256, 0, stream>>>(x, esel, sel_raw);
    k_token<<<TT / 256, 256, 0, stream>>>(sel_raw, gates, idxs, lm_sums, counts);
    k_scan<<<1, 64, 0, stream>>>(counts, offsets, cursors, tmape, tmapt, ntiles,
                                 lm_sums, out + (size_t)TT * VV);
    k_scatter<<<TT / 256, 256, 0, stream>>>(idxs, gates, cursors, perm, pgate);
    k_expert<<<NTILE_MAX, 256, 0, stream>>>(xb, kfb, vfb, perm, pgate,
                                            offsets, counts, tmape, tmapt, ntiles, out);
}

// Round 4
// 362.849 us; speedup vs baseline: 3.5550x; 1.1968x over previous
//
#include <hip/hip_runtime.h>

typedef unsigned int uint;
typedef unsigned short ushort;

#define TT 16384      // tokens = B*S
#define DD 1024       // d_model
#define EE 32         // experts
#define ESS 128       // expert size
#define VV 1024       // v dim
#define KK 4          // top-k
#define TILE 64
#define NTILE_MAX 1056   // 16384*4/64 + 32 ; == 8*132 (XCD-swizzle friendly)

typedef __attribute__((ext_vector_type(8))) short bf16x8;   // 8 bf16 = 4 VGPR
typedef __attribute__((ext_vector_type(16))) float f32x16;

// ---------------- ws layout (offsets in 4B units) ----------------
#define WS_SELRAW   0                       // 524288 f
#define WS_GATES    524288                  // 65536 f
#define WS_PGATE    589824                  // 65536 f
#define WS_STATS    655360                  // lm_sums 32 f + counts 32 i (memset region)
#define WS_LMSUMS   655360
#define WS_COUNTS   655392
#define WS_OFFSETS  655424                  // 33 i
#define WS_CURSORS  655457                  // 32 i
#define WS_NTILES   655489                  // 1 i
#define WS_TMAPE    655490                  // 1056 i
#define WS_TMAPT    656546                  // 1056 i
#define WS_IDXS     657602                  // 65536 i
#define WS_PERM     723138                  // 65536 i
// bf16 buffers (16B-aligned starts, sizes in uint units)
#define WS_XB       788736                  // x bf16 [16384][1024] -> 8388608 uints
#define WS_KF       9177344                 // keys frag-major [32][64][4][64][8] -> 2097152 uints
#define WS_VF       11274496                // values frag-major [32][32][8][64][8] -> 2097152 uints

// fp32 -> bf16 RNE
__device__ __forceinline__ ushort f2b(float f) {
    uint u = __builtin_bit_cast(uint, f);
    u = (u + 0x7fffu + ((u >> 16) & 1u)) >> 16;
    return (ushort)u;
}
__device__ __forceinline__ uint bpack(float lo, float hi) {
    return (uint)f2b(lo) | ((uint)f2b(hi) << 16);
}

// async global->LDS, 16B per lane; LDS dest = wave-uniform base + lane*16,
// global src is per-lane (m104/m173 semantics)
__device__ __forceinline__ void gload_lds16(const void* g, void* l) {
    __builtin_amdgcn_global_load_lds(
        (const __attribute__((address_space(1))) uint*)g,
        (__attribute__((address_space(3))) uint*)l, 16, 0, 0);
}

// ------------- keys -> B-fragment-major bf16 -------------
// kfb[e][ks=0..63][nf=0..3][lane=0..63][j=0..7] = keys[e][ks*16+(lane>>5)*8+j][nf*32+(lane&31)]
__global__ __launch_bounds__(256) void k_prep_k(const float* __restrict__ keys,
                                                ushort* __restrict__ kfb) {
    const int e = blockIdx.x >> 6, ks = blockIdx.x & 63;
    const int nf = threadIdx.x >> 6, l = threadIdx.x & 63;
    const int f = nf * 32 + (l & 31);
    const int d0 = ks * 16 + (l >> 5) * 8;
    const float* src = keys + ((size_t)e * DD + d0) * ESS + f;
    float v[8];
#pragma unroll
    for (int j = 0; j < 8; j++) v[j] = src[(size_t)j * ESS];
    uint4 r = { bpack(v[0], v[1]), bpack(v[2], v[3]), bpack(v[4], v[5]), bpack(v[6], v[7]) };
    const size_t off = (((size_t)e * 64 + ks) * 4 + nf) * 512 + l * 8;
    *(uint4*)(kfb + off) = r;
}

// ------------- values -> B-fragment-major bf16 -------------
// vfb[e][nv=0..31][ks=0..7][lane][j] = values[e][ks*16+(lane>>5)*8+j][nv*32+(lane&31)]
__global__ __launch_bounds__(512) void k_prep_v(const float* __restrict__ values,
                                                ushort* __restrict__ vfb) {
    const int e = blockIdx.x >> 5, nv = blockIdx.x & 31;
    const int ks = threadIdx.x >> 6, l = threadIdx.x & 63;
    const int v0 = nv * 32 + (l & 31);
    const int f0 = ks * 16 + (l >> 5) * 8;
    const float* src = values + ((size_t)e * ESS + f0) * VV + v0;
    float v[8];
#pragma unroll
    for (int j = 0; j < 8; j++) v[j] = src[(size_t)j * VV];
    uint4 r = { bpack(v[0], v[1]), bpack(v[2], v[3]), bpack(v[4], v[5]), bpack(v[6], v[7]) };
    const size_t off = (((size_t)e * 32 + nv) * 8 + ks) * 512 + l * 8;
    *(uint4*)(vfb + off) = r;
}

// ------------- router: sel_raw = X * Wsel^T (fp32!)  + fused x->bf16 ------
// fp32 on purpose: bf16 logits flip ~1% of top-4 picks -> O(1) output errors.
__global__ __launch_bounds__(256) void k_router(const float* __restrict__ x,
                                                const float* __restrict__ sel,
                                                float* __restrict__ sel_raw,
                                                uint* __restrict__ xbu) {
    __shared__ float xs[64][68];
    __shared__ float ss[32][68];
    const int tid = threadIdx.x;
    const int t0 = blockIdx.x * 64;
    const int el = tid & 31;
    const int tg = tid >> 5;
    float acc[8];
#pragma unroll
    for (int i = 0; i < 8; i++) acc[i] = 0.f;

    for (int dc = 0; dc < DD; dc += 64) {
#pragma unroll
        for (int i = 0; i < 4; i++) {
            int q = tid + 256 * i;
            int r = q >> 4, c4 = q & 15;
            size_t gi = (size_t)(t0 + r) * DD + dc + c4 * 4;
            float4 v = *(const float4*)&x[gi];
            *(float4*)&xs[r][c4 * 4] = v;
            uint2 bv = { bpack(v.x, v.y), bpack(v.z, v.w) };   // fused bf16 emit
            *(uint2*)&xbu[gi / 2] = bv;
        }
#pragma unroll
        for (int i = 0; i < 2; i++) {
            int q = tid + 256 * i;
            int e = q >> 4, c4 = q & 15;
            float4 v = *(const float4*)&sel[(size_t)e * DD + dc + c4 * 4];
            *(float4*)&ss[e][c4 * 4] = v;
        }
        __syncthreads();
#pragma unroll
        for (int d4 = 0; d4 < 16; d4++) {
            float4 sv = *(const float4*)&ss[el][d4 * 4];
#pragma unroll
            for (int i = 0; i < 8; i++) {
                float4 xv = *(const float4*)&xs[tg * 8 + i][d4 * 4];
                acc[i] += xv.x * sv.x + xv.y * sv.y + xv.z * sv.z + xv.w * sv.w;
            }
        }
        __syncthreads();
    }
#pragma unroll
    for (int i = 0; i < 8; i++)
        sel_raw[(size_t)(t0 + tg * 8 + i) * EE + el] = acc[i];
}

// ------------- per-token: lse, sigmoid, top-4, block-agg counts/lm --------
__global__ __launch_bounds__(256) void k_token(const float* __restrict__ sel_raw,
                                               float* __restrict__ gates,
                                               int* __restrict__ idxs,
                                               float* __restrict__ lm_sums,
                                               int* __restrict__ counts) {
    __shared__ int hist[EE];
    __shared__ float lmh[EE];
    const int tid = threadIdx.x;
    if (tid < EE) { hist[tid] = 0; lmh[tid] = 0.f; }
    __syncthreads();

    const int t = blockIdx.x * 256 + tid;
    float v[32];
#pragma unroll
    for (int j = 0; j < 8; j++) {
        float4 q = *(const float4*)&sel_raw[(size_t)t * EE + j * 4];
        v[j * 4 + 0] = q.x; v[j * 4 + 1] = q.y; v[j * 4 + 2] = q.z; v[j * 4 + 3] = q.w;
    }
    float m = v[0];
#pragma unroll
    for (int e = 1; e < 32; e++) m = fmaxf(m, v[e]);
    float s = 0.f;
#pragma unroll
    for (int e = 0; e < 32; e++) s += expf(v[e] - m);
    const float lse = logf(s) + m;

    float sg[32];
#pragma unroll
    for (int e = 0; e < 32; e++) sg[e] = 1.f / (1.f + expf(-v[e]));

    unsigned taken = 0u;
#pragma unroll
    for (int k = 0; k < KK; k++) {
        float best = -1.f; int bi = 0;
#pragma unroll
        for (int e = 0; e < 32; e++) {
            bool free_e = !((taken >> e) & 1u);
            if (free_e && sg[e] > best) { best = sg[e]; bi = e; }
        }
        taken |= 1u << bi;
        gates[t * KK + k] = best;
        idxs[t * KK + k] = bi;
        atomicAdd(&hist[bi], 1);
    }

#pragma unroll
    for (int e = 0; e < 32; e++) {
        float pv = expf(v[e] - lse);
#pragma unroll
        for (int o = 32; o >= 1; o >>= 1) pv += __shfl_xor(pv, o, 64);
        if ((tid & 63) == 0) atomicAdd(&lmh[e], pv);
    }
    __syncthreads();
    if (tid < EE) {
        atomicAdd(&counts[tid], hist[tid]);
        atomicAdd(&lm_sums[tid], lmh[tid]);
    }
}

// ------------- wave-parallel: scan counts, tile map, reg_loss -------------
__global__ void k_scan(const int* __restrict__ counts, int* __restrict__ offsets,
                       int* __restrict__ cursors, int* __restrict__ tmape,
                       int* __restrict__ tmapt, int* __restrict__ ntiles,
                       const float* __restrict__ lm_sums, float* __restrict__ out_reg) {
    const int lane = threadIdx.x;          // one wave of 64
    int c = (lane < EE) ? counts[lane] : 0;
    int p = c;
#pragma unroll
    for (int o = 1; o < 32; o <<= 1) { int u = __shfl_up(p, o, 64); if (lane >= o) p += u; }
    const int off = p - c;                 // exclusive prefix
    if (lane < EE) { offsets[lane] = off; cursors[lane] = off; }
    if (lane == EE - 1) offsets[EE] = p;

    int nt = (c + TILE - 1) / TILE;
    int q = nt;
#pragma unroll
    for (int o = 1; o < 32; o <<= 1) { int u = __shfl_up(q, o, 64); if (lane >= o) q += u; }
    const int tb = q - nt;
    if (lane < EE)
        for (int j = 0; j < nt; j++) { tmape[tb + j] = lane; tmapt[tb + j] = j; }
    if (lane == EE - 1) ntiles[0] = q;

    float rv = 0.f;
    if (lane < EE) {
        float pe = lm_sums[lane] * (1.f / (float)TT);
        rv = pe * logf(pe);
    }
#pragma unroll
    for (int o = 16; o >= 1; o >>= 1) rv += __shfl_down(rv, o, 64);
    if (lane == 0) out_reg[0] = rv;
}

// ------------- scatter token ids into per-expert buckets (block-agg) ------
__global__ __launch_bounds__(256) void k_scatter(const int* __restrict__ idxs,
                                                 const float* __restrict__ gates,
                                                 int* __restrict__ cursors,
                                                 int* __restrict__ perm,
                                                 float* __restrict__ pgate) {
    __shared__ int lh[EE];
    __shared__ int lbase[EE];
    const int tid = threadIdx.x;
    if (tid < EE) lh[tid] = 0;
    __syncthreads();
    const int t = blockIdx.x * 256 + tid;
    int ee[KK], rk[KK];
#pragma unroll
    for (int k = 0; k < KK; k++) {
        ee[k] = idxs[t * KK + k];
        rk[k] = atomicAdd(&lh[ee[k]], 1);
    }
    __syncthreads();
    if (tid < EE) lbase[tid] = atomicAdd(&cursors[tid], lh[tid]);
    __syncthreads();
#pragma unroll
    for (int k = 0; k < KK; k++) {
        int pos = lbase[ee[k]] + rk[k];
        perm[pos] = t;
        pgate[pos] = gates[t * KK + k];
    }
}

// ------------- bucketed expert chain: 32x32x16 bf16 MFMA -------------
// phase 1: H[64][128] = relu(Xg * keys[e]) * gate  (waves 2x2: 32 tok x 64 f each)
//   X tile staged in LDS via global_load_lds (gathered rows), XOR-swizzled so
//   A ds_read_b128 is bank-conflict-free; B streamed frag-major with 4-deep
//   explicit register prefetch (compiler won't pipeline on its own: r3 VGPR=60).
// phase 2: OUT[64][1024] += H * values[e], V double-buffered 2 nv ahead.
// A (32x32x16): row=lane&31, k=(lane>>5)*8+j.  B: col=lane&31, same k.
// C/D (m74/m101-verified): col=lane&31, row=(reg&3)+8*(reg>>2)+4*(lane>>5).
__global__ __launch_bounds__(256, 2) void k_expert(
    const ushort* __restrict__ xb, const ushort* __restrict__ kfb,
    const ushort* __restrict__ vfb,
    const int* __restrict__ perm, const float* __restrict__ pgate,
    const int* __restrict__ offsets, const int* __restrict__ counts,
    const int* __restrict__ tmape, const int* __restrict__ tmapt,
    const int* __restrict__ ntiles, float* __restrict__ out)
{
    __shared__ __align__(1024) char xsb[64 * 512];  // X chunk: 64 rows x 256 cols bf16, swizzled
    __shared__ __align__(16) ushort hs[64][128];    // H bf16, XOR-swizzled cols
    __shared__ float gl[64];
    __shared__ int tl[64];

    // bijective XCD swizzle: 1056 = 8*132 -> per-XCD contiguous expert-major chunk
    const int bid = (blockIdx.x & 7) * 132 + (blockIdx.x >> 3);
    if (bid >= ntiles[0]) return;
    const int e = tmape[bid];
    const int base = offsets[e] + tmapt[bid] * TILE;
    const int nr = min(TILE, offsets[e] + counts[e] - base);
    const int tid = threadIdx.x;

    if (tid < 64) {
        int tok = 0; float g = 0.f;
        if (tid < nr) { tok = perm[base + tid]; g = pgate[base + tid]; }
        tl[tid] = tok; gl[tid] = g;
    }
    __syncthreads();

    const int lane = tid & 63, wid = tid >> 6;
    const int wm = wid >> 1, wn = wid & 1;      // 2x2 wave grid
    const int l31 = lane & 31, l5 = lane >> 5;

    const char* xbytes = (const char*)xb;
    const ushort* kb = kfb + ((size_t)e * 256 + wn * 2) * 512 + lane * 8;

    // per-lane staging geometry (2 rows per 1KB instruction)
    int srow[8]; const char* ssrc[8];
#pragma unroll
    for (int i = 0; i < 8; i++) {
        int ldsb = (wid * 8 + i) * 1024;
        int lb = ldsb + lane * 16;
        int row = lb >> 9;                      // /512
        int colb = lb & 511;
        srow[i] = ldsb;
        ssrc[i] = xbytes + (size_t)tl[row] * 2048 + (colb ^ ((row & 31) << 4));
    }

    f32x16 acc0, acc1;
#pragma unroll
    for (int r = 0; r < 16; r++) { acc0[r] = 0.f; acc1[r] = 0.f; }

    // 4-deep B prefetch (ks = 0..63 global)
    bf16x8 b0p[4], b1p[4];
#pragma unroll
    for (int j = 0; j < 4; j++) {
        b0p[j] = *(const bf16x8*)(kb + (size_t)j * 2048);
        b1p[j] = *(const bf16x8*)(kb + (size_t)j * 2048 + 512);
    }

    const int aRrow = wm * 32 + l31;            // A-frag row for this lane
    for (int c = 0; c < 4; c++) {
        // stage chunk c (cols c*256 .. +256)
#pragma unroll
        for (int i = 0; i < 8; i++)
            gload_lds16(ssrc[i] + c * 512, xsb + srow[i]);
        __syncthreads();                        // drains vmcnt -> chunk staged

#pragma unroll
        for (int ksl = 0; ksl < 16; ksl++) {
            bf16x8 a = *(const bf16x8*)(xsb + aRrow * 512 +
                                        ((ksl * 32 + l5 * 16) ^ (l31 << 4)));
            int ks = c * 16 + ksl;
            acc0 = __builtin_amdgcn_mfma_f32_32x32x16_bf16(a, b0p[ksl & 3], acc0, 0, 0, 0);
            acc1 = __builtin_amdgcn_mfma_f32_32x32x16_bf16(a, b1p[ksl & 3], acc1, 0, 0, 0);
            if (ks + 4 < 64) {                  // rotate prefetch slot
                b0p[ksl & 3] = *(const bf16x8*)(kb + (size_t)(ks + 4) * 2048);
                b1p[ksl & 3] = *(const bf16x8*)(kb + (size_t)(ks + 4) * 2048 + 512);
            }
        }
        __syncthreads();                        // all waves done reading xsb
    }

    // relu * gate -> swizzled bf16 H in LDS
#pragma unroll
    for (int r = 0; r < 16; r++) {
        int row = (r & 3) + 8 * (r >> 2) + 4 * l5;
        int grow = wm * 32 + row;
        float g = gl[grow];
        int c0 = wn * 64 + l31;
        int c1 = c0 + 32;
        int sw = (grow & 7) << 3;
        hs[grow][c0 ^ sw] = f2b(fmaxf(acc0[r], 0.f) * g);
        hs[grow][c1 ^ sw] = f2b(fmaxf(acc1[r], 0.f) * g);
    }
    __syncthreads();

    // ---- phase 2: A-frags (H) hoisted to regs, V double-buffered ----
    bf16x8 af[8];
    const int hr = wm * 32 + l31;
    const int hsw = (hr & 7) << 3;
#pragma unroll
    for (int ks = 0; ks < 8; ks++) {
        int cc = ks * 16 + l5 * 8;
        af[ks] = *(const bf16x8*)&hs[hr][cc ^ hsw];
    }

    int ptok[16]; bool pv[16];
#pragma unroll
    for (int r = 0; r < 16; r++) {
        int row = wm * 32 + (r & 3) + 8 * (r >> 2) + 4 * l5;
        ptok[r] = tl[row]; pv[r] = (row < nr);
    }

    const ushort* vb = vfb + ((size_t)e * 32 + wn * 16) * 4096 + lane * 8;
    bf16x8 vp[2][8];
#pragma unroll
    for (int ks = 0; ks < 8; ks++) {
        vp[0][ks] = *(const bf16x8*)(vb + (size_t)ks * 512);
        vp[1][ks] = *(const bf16x8*)(vb + (size_t)(8 + ks) * 512);
    }

#pragma unroll
    for (int nv = 0; nv < 16; nv++) {
        f32x16 acc;
#pragma unroll
        for (int r = 0; r < 16; r++) acc[r] = 0.f;
#pragma unroll
        for (int ks = 0; ks < 8; ks++)
            acc = __builtin_amdgcn_mfma_f32_32x32x16_bf16(af[ks], vp[nv & 1][ks], acc, 0, 0, 0);
        if (nv + 2 < 16) {                      // refill the buffer just consumed
#pragma unroll
            for (int ks = 0; ks < 8; ks++)
                vp[nv & 1][ks] = *(const bf16x8*)(vb + ((size_t)(nv + 2) * 8 + ks) * 512);
        }
        const int colb = wn * 512 + nv * 32 + l31;
#pragma unroll
        for (int r = 0; r < 16; r++)
            if (pv[r])
                atomicAdd(&out[(size_t)ptok[r] * VV + colb], acc[r]);
    }
}

// --------------------------------------------------------------------------
extern "C" void kernel_launch(void* const* d_in, const int* in_sizes, int n_in,
                              void* d_out, int out_size, void* d_ws, size_t ws_size,
                              hipStream_t stream) {
    const float* x      = (const float*)d_in[0];
    const float* keys   = (const float*)d_in[1];
    const float* values = (const float*)d_in[2];
    const float* esel   = (const float*)d_in[3];
    float* out = (float*)d_out;

    float* wsf = (float*)d_ws;
    int*   wsi = (int*)d_ws;

    float* sel_raw = wsf + WS_SELRAW;
    float* gates   = wsf + WS_GATES;
    float* pgate   = wsf + WS_PGATE;
    float* lm_sums = wsf + WS_LMSUMS;
    int*   counts  = wsi + WS_COUNTS;
    int*   offsets = wsi + WS_OFFSETS;
    int*   cursors = wsi + WS_CURSORS;
    int*   ntiles  = wsi + WS_NTILES;
    int*   tmape   = wsi + WS_TMAPE;
    int*   tmapt   = wsi + WS_TMAPT;
    int*   idxs    = wsi + WS_IDXS;
    int*   perm    = wsi + WS_PERM;
    uint*   xbu = (uint*)(wsf + WS_XB);
    ushort* xb  = (ushort*)xbu;
    ushort* kfb = (ushort*)(wsf + WS_KF);
    ushort* vfb = (ushort*)(wsf + WS_VF);

    hipMemsetAsync(d_out, 0, (size_t)TT * VV * sizeof(float), stream);
    hipMemsetAsync(wsf + WS_STATS, 0, 64 * sizeof(float), stream);

    k_prep_k<<<EE * 64, 256, 0, stream>>>(keys, kfb);
    k_prep_v<<<EE * 32, 512, 0, stream>>>(values, vfb);

    k_router<<<TT / 64, 256, 0, stream>>>(x, esel, sel_raw, xbu);
    k_token<<<TT / 256, 256, 0, stream>>>(sel_raw, gates, idxs, lm_sums, counts);
    k_scan<<<1, 64, 0, stream>>>(counts, offsets, cursors, tmape, tmapt, ntiles,
                                 lm_sums, out + (size_t)TT * VV);
    k_scatter<<<TT / 256, 256, 0, stream>>>(idxs, gates, cursors, perm, pgate);
    k_expert<<<NTILE_MAX, 256, 0, stream>>>(xb, kfb, vfb, perm, pgate,
                                            offsets, counts, tmape, tmapt, ntiles, out);
}

// Round 5
// 256.851 us; speedup vs baseline: 5.0222x; 1.4127x over previous
//
#include <hip/hip_runtime.h>

typedef unsigned int uint;
typedef unsigned short ushort;

#define TT 16384      // tokens = B*S
#define DD 1024       // d_model
#define EE 32         // experts
#define ESS 128       // expert size
#define VV 1024       // v dim
#define KK 4          // top-k
#define TILE 64
#define NTILE_MAX 1056   // 16384*4/64 + 32 ; == 8*132 (XCD-swizzle friendly)

typedef __attribute__((ext_vector_type(8))) short bf16x8;   // 8 bf16 = 4 VGPR
typedef __attribute__((ext_vector_type(16))) float f32x16;

// ---------------- ws layout (offsets in 4B units) ----------------
#define WS_SELRAW   0                       // 524288 f
#define WS_GATES    524288                  // 65536 f
#define WS_PGATE    589824                  // 65536 f
#define WS_STATS    655360                  // lm_sums 32 f + counts 32 i (memset region)
#define WS_LMSUMS   655360
#define WS_COUNTS   655392
#define WS_OFFSETS  655424                  // 33 i
#define WS_CURSORS  655457                  // 32 i
#define WS_NTILES   655489                  // 1 i
#define WS_TMAPE    655490                  // 1056 i
#define WS_TMAPT    656546                  // 1056 i
#define WS_IDXS     657602                  // 65536 i
#define WS_PERM     723138                  // 65536 i
// bf16 buffers (16B-aligned starts, sizes in uint units)
#define WS_XB       788736                  // x bf16 [16384][1024] -> 8388608 uints
#define WS_KF       9177344                 // keys frag-major [32][64][4][64][8] -> 2097152 uints
#define WS_VF       11274496                // values frag-major [32][32][8][64][8] -> 2097152 uints
#define WS_ISLOT    13371648                // token -> 4 slot ids, 65536 i
#define WS_STG      13437184                // slot partials bf16 [65536][1024] -> 33554432 uints
#define WS_NEED_U   46991616ull             // total uints needed for staging path

// fp32 -> bf16 RNE
__device__ __forceinline__ ushort f2b(float f) {
    uint u = __builtin_bit_cast(uint, f);
    u = (u + 0x7fffu + ((u >> 16) & 1u)) >> 16;
    return (ushort)u;
}
__device__ __forceinline__ uint bpack(float lo, float hi) {
    return (uint)f2b(lo) | ((uint)f2b(hi) << 16);
}
__device__ __forceinline__ float b2f(ushort b) {
    uint u = (uint)b << 16;
    return __builtin_bit_cast(float, u);
}

// async global->LDS, 16B per lane; LDS dest = wave-uniform base + lane*16,
// global src is per-lane (m104/m173 semantics)
__device__ __forceinline__ void gload_lds16(const void* g, void* l) {
    __builtin_amdgcn_global_load_lds(
        (const __attribute__((address_space(1))) uint*)g,
        (__attribute__((address_space(3))) uint*)l, 16, 0, 0);
}

// ------------- keys -> B-fragment-major bf16 -------------
// kfb[e][ks=0..63][nf=0..3][lane=0..63][j=0..7] = keys[e][ks*16+(lane>>5)*8+j][nf*32+(lane&31)]
__global__ __launch_bounds__(256) void k_prep_k(const float* __restrict__ keys,
                                                ushort* __restrict__ kfb) {
    const int e = blockIdx.x >> 6, ks = blockIdx.x & 63;
    const int nf = threadIdx.x >> 6, l = threadIdx.x & 63;
    const int f = nf * 32 + (l & 31);
    const int d0 = ks * 16 + (l >> 5) * 8;
    const float* src = keys + ((size_t)e * DD + d0) * ESS + f;
    float v[8];
#pragma unroll
    for (int j = 0; j < 8; j++) v[j] = src[(size_t)j * ESS];
    uint4 r = { bpack(v[0], v[1]), bpack(v[2], v[3]), bpack(v[4], v[5]), bpack(v[6], v[7]) };
    const size_t off = (((size_t)e * 64 + ks) * 4 + nf) * 512 + l * 8;
    *(uint4*)(kfb + off) = r;
}

// ------------- values -> B-fragment-major bf16 -------------
// vfb[e][nv=0..31][ks=0..7][lane][j] = values[e][ks*16+(lane>>5)*8+j][nv*32+(lane&31)]
__global__ __launch_bounds__(512) void k_prep_v(const float* __restrict__ values,
                                                ushort* __restrict__ vfb) {
    const int e = blockIdx.x >> 5, nv = blockIdx.x & 31;
    const int ks = threadIdx.x >> 6, l = threadIdx.x & 63;
    const int v0 = nv * 32 + (l & 31);
    const int f0 = ks * 16 + (l >> 5) * 8;
    const float* src = values + ((size_t)e * ESS + f0) * VV + v0;
    float v[8];
#pragma unroll
    for (int j = 0; j < 8; j++) v[j] = src[(size_t)j * VV];
    uint4 r = { bpack(v[0], v[1]), bpack(v[2], v[3]), bpack(v[4], v[5]), bpack(v[6], v[7]) };
    const size_t off = (((size_t)e * 32 + nv) * 8 + ks) * 512 + l * 8;
    *(uint4*)(vfb + off) = r;
}

// ------------- router: sel_raw = X * Wsel^T (fp32!)  + fused x->bf16 ------
// fp32 on purpose: bf16 logits flip ~1% of top-4 picks -> O(1) output errors.
__global__ __launch_bounds__(256) void k_router(const float* __restrict__ x,
                                                const float* __restrict__ sel,
                                                float* __restrict__ sel_raw,
                                                uint* __restrict__ xbu) {
    __shared__ float xs[64][68];
    __shared__ float ss[32][68];
    const int tid = threadIdx.x;
    const int t0 = blockIdx.x * 64;
    const int el = tid & 31;
    const int tg = tid >> 5;
    float acc[8];
#pragma unroll
    for (int i = 0; i < 8; i++) acc[i] = 0.f;

    for (int dc = 0; dc < DD; dc += 64) {
#pragma unroll
        for (int i = 0; i < 4; i++) {
            int q = tid + 256 * i;
            int r = q >> 4, c4 = q & 15;
            size_t gi = (size_t)(t0 + r) * DD + dc + c4 * 4;
            float4 v = *(const float4*)&x[gi];
            *(float4*)&xs[r][c4 * 4] = v;
            uint2 bv = { bpack(v.x, v.y), bpack(v.z, v.w) };   // fused bf16 emit
            *(uint2*)&xbu[gi / 2] = bv;
        }
#pragma unroll
        for (int i = 0; i < 2; i++) {
            int q = tid + 256 * i;
            int e = q >> 4, c4 = q & 15;
            float4 v = *(const float4*)&sel[(size_t)e * DD + dc + c4 * 4];
            *(float4*)&ss[e][c4 * 4] = v;
        }
        __syncthreads();
#pragma unroll
        for (int d4 = 0; d4 < 16; d4++) {
            float4 sv = *(const float4*)&ss[el][d4 * 4];
#pragma unroll
            for (int i = 0; i < 8; i++) {
                float4 xv = *(const float4*)&xs[tg * 8 + i][d4 * 4];
                acc[i] += xv.x * sv.x + xv.y * sv.y + xv.z * sv.z + xv.w * sv.w;
            }
        }
        __syncthreads();
    }
#pragma unroll
    for (int i = 0; i < 8; i++)
        sel_raw[(size_t)(t0 + tg * 8 + i) * EE + el] = acc[i];
}

// ------------- per-token: lse, sigmoid, top-4, block-agg counts/lm --------
__global__ __launch_bounds__(256) void k_token(const float* __restrict__ sel_raw,
                                               float* __restrict__ gates,
                                               int* __restrict__ idxs,
                                               float* __restrict__ lm_sums,
                                               int* __restrict__ counts) {
    __shared__ int hist[EE];
    __shared__ float lmh[EE];
    const int tid = threadIdx.x;
    if (tid < EE) { hist[tid] = 0; lmh[tid] = 0.f; }
    __syncthreads();

    const int t = blockIdx.x * 256 + tid;
    float v[32];
#pragma unroll
    for (int j = 0; j < 8; j++) {
        float4 q = *(const float4*)&sel_raw[(size_t)t * EE + j * 4];
        v[j * 4 + 0] = q.x; v[j * 4 + 1] = q.y; v[j * 4 + 2] = q.z; v[j * 4 + 3] = q.w;
    }
    float m = v[0];
#pragma unroll
    for (int e = 1; e < 32; e++) m = fmaxf(m, v[e]);
    float s = 0.f;
#pragma unroll
    for (int e = 0; e < 32; e++) s += expf(v[e] - m);
    const float lse = logf(s) + m;

    float sg[32];
#pragma unroll
    for (int e = 0; e < 32; e++) sg[e] = 1.f / (1.f + expf(-v[e]));

    unsigned taken = 0u;
#pragma unroll
    for (int k = 0; k < KK; k++) {
        float best = -1.f; int bi = 0;
#pragma unroll
        for (int e = 0; e < 32; e++) {
            bool free_e = !((taken >> e) & 1u);
            if (free_e && sg[e] > best) { best = sg[e]; bi = e; }
        }
        taken |= 1u << bi;
        gates[t * KK + k] = best;
        idxs[t * KK + k] = bi;
        atomicAdd(&hist[bi], 1);
    }

#pragma unroll
    for (int e = 0; e < 32; e++) {
        float pv = expf(v[e] - lse);
#pragma unroll
        for (int o = 32; o >= 1; o >>= 1) pv += __shfl_xor(pv, o, 64);
        if ((tid & 63) == 0) atomicAdd(&lmh[e], pv);
    }
    __syncthreads();
    if (tid < EE) {
        atomicAdd(&counts[tid], hist[tid]);
        atomicAdd(&lm_sums[tid], lmh[tid]);
    }
}

// ------------- wave-parallel: scan counts, tile map, reg_loss -------------
__global__ void k_scan(const int* __restrict__ counts, int* __restrict__ offsets,
                       int* __restrict__ cursors, int* __restrict__ tmape,
                       int* __restrict__ tmapt, int* __restrict__ ntiles,
                       const float* __restrict__ lm_sums, float* __restrict__ out_reg) {
    const int lane = threadIdx.x;          // one wave of 64
    int c = (lane < EE) ? counts[lane] : 0;
    int p = c;
#pragma unroll
    for (int o = 1; o < 32; o <<= 1) { int u = __shfl_up(p, o, 64); if (lane >= o) p += u; }
    const int off = p - c;                 // exclusive prefix
    if (lane < EE) { offsets[lane] = off; cursors[lane] = off; }
    if (lane == EE - 1) offsets[EE] = p;

    int nt = (c + TILE - 1) / TILE;
    int q = nt;
#pragma unroll
    for (int o = 1; o < 32; o <<= 1) { int u = __shfl_up(q, o, 64); if (lane >= o) q += u; }
    const int tb = q - nt;
    if (lane < EE)
        for (int j = 0; j < nt; j++) { tmape[tb + j] = lane; tmapt[tb + j] = j; }
    if (lane == EE - 1) ntiles[0] = q;

    float rv = 0.f;
    if (lane < EE) {
        float pe = lm_sums[lane] * (1.f / (float)TT);
        rv = pe * logf(pe);
    }
#pragma unroll
    for (int o = 16; o >= 1; o >>= 1) rv += __shfl_down(rv, o, 64);
    if (lane == 0) out_reg[0] = rv;
}

// ------------- scatter token ids into per-expert buckets (block-agg) ------
__global__ __launch_bounds__(256) void k_scatter(const int* __restrict__ idxs,
                                                 const float* __restrict__ gates,
                                                 int* __restrict__ cursors,
                                                 int* __restrict__ perm,
                                                 float* __restrict__ pgate,
                                                 int* __restrict__ islot) {
    __shared__ int lh[EE];
    __shared__ int lbase[EE];
    const int tid = threadIdx.x;
    if (tid < EE) lh[tid] = 0;
    __syncthreads();
    const int t = blockIdx.x * 256 + tid;
    int ee[KK], rk[KK];
#pragma unroll
    for (int k = 0; k < KK; k++) {
        ee[k] = idxs[t * KK + k];
        rk[k] = atomicAdd(&lh[ee[k]], 1);
    }
    __syncthreads();
    if (tid < EE) lbase[tid] = atomicAdd(&cursors[tid], lh[tid]);
    __syncthreads();
#pragma unroll
    for (int k = 0; k < KK; k++) {
        int pos = lbase[ee[k]] + rk[k];
        perm[pos] = t;
        pgate[pos] = gates[t * KK + k];
        islot[t * KK + k] = pos;
    }
}

// ------------- bucketed expert chain: 32x32x16 bf16 MFMA -------------
// phase 1: H[64][128] = relu(Xg * keys[e]) * gate  (waves 2x2: 32 tok x 64 f each)
//   X staged to LDS via global_load_lds (gathered rows, XOR-swizzled A reads);
//   B frag-major global stream with branchless 8-deep register prefetch.
// phase 2: OUT partials: STG=1 -> bf16 plain stores into per-slot staging
//   (no atomics; combine kernel reduces K slots/token); STG=0 -> fp32 atomics.
// A (32x32x16): row=lane&31, k=(lane>>5)*8+j.  B: col=lane&31, same k.
// C/D (m74/m101-verified): col=lane&31, row=(reg&3)+8*(reg>>2)+4*(lane>>5).
template <bool STG>
__global__ __launch_bounds__(256, 2) void k_expert(
    const ushort* __restrict__ xb, const ushort* __restrict__ kfb,
    const ushort* __restrict__ vfb,
    const int* __restrict__ perm, const float* __restrict__ pgate,
    const int* __restrict__ offsets, const int* __restrict__ counts,
    const int* __restrict__ tmape, const int* __restrict__ tmapt,
    const int* __restrict__ ntiles, ushort* __restrict__ stg,
    float* __restrict__ out)
{
    __shared__ __align__(1024) char xsb[64 * 512];  // X chunk: 64 rows x 256 cols bf16, swizzled
    __shared__ __align__(16) ushort hs[64][128];    // H bf16, XOR-swizzled cols
    __shared__ float gl[64];
    __shared__ int tl[64];

    // bijective XCD swizzle: 1056 = 8*132 -> per-XCD contiguous expert-major chunk
    const int bid = (blockIdx.x & 7) * 132 + (blockIdx.x >> 3);
    if (bid >= ntiles[0]) return;
    const int e = tmape[bid];
    const int base = offsets[e] + tmapt[bid] * TILE;
    const int nr = min(TILE, offsets[e] + counts[e] - base);
    const int tid = threadIdx.x;

    if (tid < 64) {
        int tok = 0; float g = 0.f;
        if (tid < nr) { tok = perm[base + tid]; g = pgate[base + tid]; }
        tl[tid] = tok; gl[tid] = g;
    }
    __syncthreads();

    const int lane = tid & 63, wid = tid >> 6;
    const int wm = wid >> 1, wn = wid & 1;      // 2x2 wave grid
    const int l31 = lane & 31, l5 = lane >> 5;

    const char* xbytes = (const char*)xb;
    const ushort* kb = kfb + ((size_t)e * 256 + wn * 2) * 512 + lane * 8;

    // per-lane staging geometry (2 rows per 1KB instruction)
    int srow[8]; const char* ssrc[8];
#pragma unroll
    for (int i = 0; i < 8; i++) {
        int ldsb = (wid * 8 + i) * 1024;
        int lb = ldsb + lane * 16;
        int row = lb >> 9;                      // /512
        int colb = lb & 511;
        srow[i] = ldsb;
        ssrc[i] = xbytes + (size_t)tl[row] * 2048 + (colb ^ ((row & 31) << 4));
    }

    f32x16 acc0, acc1;
#pragma unroll
    for (int r = 0; r < 16; r++) { acc0[r] = 0.f; acc1[r] = 0.f; }

    // 8-deep branchless B prefetch (ks = 0..63 global; wrap re-reads L2-hot lines)
    bf16x8 b0p[8], b1p[8];
#pragma unroll
    for (int j = 0; j < 8; j++) {
        b0p[j] = *(const bf16x8*)(kb + (size_t)j * 2048);
        b1p[j] = *(const bf16x8*)(kb + (size_t)j * 2048 + 512);
    }

    const int aRrow = wm * 32 + l31;            // A-frag row for this lane
    for (int c = 0; c < 4; c++) {
        // stage chunk c (cols c*256 .. +256)
#pragma unroll
        for (int i = 0; i < 8; i++)
            gload_lds16(ssrc[i] + c * 512, xsb + srow[i]);
        __syncthreads();                        // drains vmcnt -> chunk staged

#pragma unroll
        for (int ksl = 0; ksl < 16; ksl++) {
            bf16x8 a = *(const bf16x8*)(xsb + aRrow * 512 +
                                        ((ksl * 32 + l5 * 16) ^ (l31 << 4)));
            int ks = c * 16 + ksl;
            acc0 = __builtin_amdgcn_mfma_f32_32x32x16_bf16(a, b0p[ksl & 7], acc0, 0, 0, 0);
            acc1 = __builtin_amdgcn_mfma_f32_32x32x16_bf16(a, b1p[ksl & 7], acc1, 0, 0, 0);
            int nk = (ks + 8) & 63;             // branchless refill of the slot just used
            b0p[ksl & 7] = *(const bf16x8*)(kb + (size_t)nk * 2048);
            b1p[ksl & 7] = *(const bf16x8*)(kb + (size_t)nk * 2048 + 512);
        }
        __syncthreads();                        // all waves done reading xsb
    }

    // relu * gate -> swizzled bf16 H in LDS
#pragma unroll
    for (int r = 0; r < 16; r++) {
        int row = (r & 3) + 8 * (r >> 2) + 4 * l5;
        int grow = wm * 32 + row;
        float g = gl[grow];
        int c0 = wn * 64 + l31;
        int c1 = c0 + 32;
        int sw = (grow & 7) << 3;
        hs[grow][c0 ^ sw] = f2b(fmaxf(acc0[r], 0.f) * g);
        hs[grow][c1 ^ sw] = f2b(fmaxf(acc1[r], 0.f) * g);
    }
    __syncthreads();

    // ---- phase 2: A-frags (H) hoisted to regs, V double-buffered ----
    bf16x8 af[8];
    const int hr = wm * 32 + l31;
    const int hsw = (hr & 7) << 3;
#pragma unroll
    for (int ks = 0; ks < 8; ks++) {
        int cc = ks * 16 + l5 * 8;
        af[ks] = *(const bf16x8*)&hs[hr][cc ^ hsw];
    }

    int ptok[16]; int prow[16]; bool pv[16];
#pragma unroll
    for (int r = 0; r < 16; r++) {
        int row = wm * 32 + (r & 3) + 8 * (r >> 2) + 4 * l5;
        prow[r] = row; ptok[r] = tl[row]; pv[r] = (row < nr);
    }

    const ushort* vb = vfb + ((size_t)e * 32 + wn * 16) * 4096 + lane * 8;
    bf16x8 vp[2][8];
#pragma unroll
    for (int ks = 0; ks < 8; ks++) {
        vp[0][ks] = *(const bf16x8*)(vb + (size_t)ks * 512);
        vp[1][ks] = *(const bf16x8*)(vb + (size_t)(8 + ks) * 512);
    }

#pragma unroll
    for (int nv = 0; nv < 16; nv++) {
        f32x16 acc;
#pragma unroll
        for (int r = 0; r < 16; r++) acc[r] = 0.f;
#pragma unroll
        for (int ks = 0; ks < 8; ks++)
            acc = __builtin_amdgcn_mfma_f32_32x32x16_bf16(af[ks], vp[nv & 1][ks], acc, 0, 0, 0);
        if (nv + 2 < 16) {                      // refill the buffer just consumed
#pragma unroll
            for (int ks = 0; ks < 8; ks++)
                vp[nv & 1][ks] = *(const bf16x8*)(vb + ((size_t)(nv + 2) * 8 + ks) * 512);
        }
        const int colb = wn * 512 + nv * 32 + l31;
#pragma unroll
        for (int r = 0; r < 16; r++) {
            if (!pv[r]) continue;
            if (STG)
                stg[(size_t)(base + prow[r]) * VV + colb] = f2b(acc[r]);
            else
                atomicAdd(&out[(size_t)ptok[r] * VV + colb], acc[r]);
        }
    }
}

// ------------- combine: out[t] = sum_k stg[islot[t][k]]  (streaming) ------
__global__ __launch_bounds__(256) void k_combine(const ushort* __restrict__ stg,
                                                 const int* __restrict__ islot,
                                                 float* __restrict__ out) {
    const int tid = threadIdx.x;
    const int t = blockIdx.x * 2 + (tid >> 7);      // 2 tokens/block
    const int c8 = (tid & 127) * 8;                 // 8 cols per thread
    const int4 sl = *(const int4*)&islot[t * KK];
    float acc[8];
#pragma unroll
    for (int j = 0; j < 8; j++) acc[j] = 0.f;
    const int slots[4] = { sl.x, sl.y, sl.z, sl.w };
#pragma unroll
    for (int k = 0; k < KK; k++) {
        bf16x8 v = *(const bf16x8*)(stg + (size_t)slots[k] * VV + c8);
#pragma unroll
        for (int j = 0; j < 8; j++) acc[j] += b2f((ushort)v[j]);
    }
    float4 o0 = { acc[0], acc[1], acc[2], acc[3] };
    float4 o1 = { acc[4], acc[5], acc[6], acc[7] };
    *(float4*)&out[(size_t)t * VV + c8] = o0;
    *(float4*)&out[(size_t)t * VV + c8 + 4] = o1;
}

// --------------------------------------------------------------------------
extern "C" void kernel_launch(void* const* d_in, const int* in_sizes, int n_in,
                              void* d_out, int out_size, void* d_ws, size_t ws_size,
                              hipStream_t stream) {
    const float* x      = (const float*)d_in[0];
    const float* keys   = (const float*)d_in[1];
    const float* values = (const float*)d_in[2];
    const float* esel   = (const float*)d_in[3];
    float* out = (float*)d_out;

    float* wsf = (float*)d_ws;
    int*   wsi = (int*)d_ws;

    float* sel_raw = wsf + WS_SELRAW;
    float* gates   = wsf + WS_GATES;
    float* pgate   = wsf + WS_PGATE;
    float* lm_sums = wsf + WS_LMSUMS;
    int*   counts  = wsi + WS_COUNTS;
    int*   offsets = wsi + WS_OFFSETS;
    int*   cursors = wsi + WS_CURSORS;
    int*   ntiles  = wsi + WS_NTILES;
    int*   tmape   = wsi + WS_TMAPE;
    int*   tmapt   = wsi + WS_TMAPT;
    int*   idxs    = wsi + WS_IDXS;
    int*   perm    = wsi + WS_PERM;
    int*   islot   = wsi + WS_ISLOT;
    uint*   xbu = (uint*)(wsf + WS_XB);
    ushort* xb  = (ushort*)xbu;
    ushort* kfb = (ushort*)(wsf + WS_KF);
    ushort* vfb = (ushort*)(wsf + WS_VF);
    ushort* stg = (ushort*)(wsf + WS_STG);

    const bool use_stg = ws_size >= WS_NEED_U * 4ull;

    if (!use_stg)   // atomic fallback needs a zeroed accumulator
        hipMemsetAsync(d_out, 0, (size_t)TT * VV * sizeof(float), stream);
    hipMemsetAsync(wsf + WS_STATS, 0, 64 * sizeof(float), stream);

    k_prep_k<<<EE * 64, 256, 0, stream>>>(keys, kfb);
    k_prep_v<<<EE * 32, 512, 0, stream>>>(values, vfb);

    k_router<<<TT / 64, 256, 0, stream>>>(x, esel, sel_raw, xbu);
    k_token<<<TT / 256, 256, 0, stream>>>(sel_raw, gates, idxs, lm_sums, counts);
    k_scan<<<1, 64, 0, stream>>>(counts, offsets, cursors, tmape, tmapt, ntiles,
                                 lm_sums, out + (size_t)TT * VV);
    k_scatter<<<TT / 256, 256, 0, stream>>>(idxs, gates, cursors, perm, pgate, islot);
    if (use_stg) {
        k_expert<true><<<NTILE_MAX, 256, 0, stream>>>(xb, kfb, vfb, perm, pgate,
                                                      offsets, counts, tmape, tmapt,
                                                      ntiles, stg, out);
        k_combine<<<TT / 2, 256, 0, stream>>>(stg, islot, out);
    } else {
        k_expert<false><<<NTILE_MAX, 256, 0, stream>>>(xb, kfb, vfb, perm, pgate,
                                                       offsets, counts, tmape, tmapt,
                                                       ntiles, stg, out);
    }
}

// Round 6
// 219.266 us; speedup vs baseline: 5.8830x; 1.1714x over previous
//
#include <hip/hip_runtime.h>

typedef unsigned int uint;
typedef unsigned short ushort;

#define TT 16384      // tokens = B*S
#define DD 1024       // d_model
#define EE 32         // experts
#define ESS 128       // expert size
#define VV 1024       // v dim
#define KK 4          // top-k
#define TILE 64
#define NTILE_MAX 1056   // 16384*4/64 + 32 ; == 8*132 (XCD-swizzle friendly)

typedef __attribute__((ext_vector_type(8))) short bf16x8;   // 8 bf16 = 4 VGPR
typedef __attribute__((ext_vector_type(16))) float f32x16;

// ---------------- ws layout (offsets in 4B units) ----------------
#define WS_SELRAW   0                       // 524288 f (unused now, kept for layout stability)
#define WS_GATES    524288                  // 65536 f
#define WS_PGATE    589824                  // 65536 f
#define WS_STATS    655360                  // lm_sums 32 f + counts 32 i (memset region)
#define WS_LMSUMS   655360
#define WS_COUNTS   655392
#define WS_OFFSETS  655424                  // 33 i
#define WS_CURSORS  655457                  // 32 i
#define WS_NTILES   655489                  // 1 i
#define WS_TMAPE    655490                  // 1056 i
#define WS_TMAPT    656546                  // 1056 i
#define WS_IDXS     657602                  // 65536 i
#define WS_PERM     723138                  // 65536 i
// bf16 buffers (16B-aligned starts, sizes in uint units)
#define WS_XB       788736                  // x bf16 [16384][1024] -> 8388608 uints
#define WS_KF       9177344                 // keys frag-major [32][64][4][64][8] -> 2097152 uints
#define WS_VF       11274496                // values frag-major [32][32][8][64][8] -> 2097152 uints
#define WS_ISLOT    13371648                // token -> 4 slot ids, 65536 i
#define WS_STG      13437184                // slot partials bf16 [65536][1024] -> 33554432 uints
#define WS_NEED_U   46991616ull             // total uints needed for staging path
// router partials [4][TT][EE] f32 (2097152 f) alias onto WS_STG (written later by
// k_expert) or, in the fallback, onto WS_KF (written later by k_prep_k -- which is
// therefore launched AFTER k_token consumes the partials).

// fp32 -> bf16 RNE
__device__ __forceinline__ ushort f2b(float f) {
    uint u = __builtin_bit_cast(uint, f);
    u = (u + 0x7fffu + ((u >> 16) & 1u)) >> 16;
    return (ushort)u;
}
__device__ __forceinline__ uint bpack(float lo, float hi) {
    return (uint)f2b(lo) | ((uint)f2b(hi) << 16);
}
__device__ __forceinline__ float b2f(ushort b) {
    uint u = (uint)b << 16;
    return __builtin_bit_cast(float, u);
}

// async global->LDS, 16B per lane; LDS dest = wave-uniform base + lane*16,
// global src is per-lane (m104/m173 semantics)
__device__ __forceinline__ void gload_lds16(const void* g, void* l) {
    __builtin_amdgcn_global_load_lds(
        (const __attribute__((address_space(1))) uint*)g,
        (__attribute__((address_space(3))) uint*)l, 16, 0, 0);
}

// ------------- keys -> B-fragment-major bf16 -------------
// kfb[e][ks=0..63][nf=0..3][lane=0..63][j=0..7] = keys[e][ks*16+(lane>>5)*8+j][nf*32+(lane&31)]
__global__ __launch_bounds__(256) void k_prep_k(const float* __restrict__ keys,
                                                ushort* __restrict__ kfb) {
    const int e = blockIdx.x >> 6, ks = blockIdx.x & 63;
    const int nf = threadIdx.x >> 6, l = threadIdx.x & 63;
    const int f = nf * 32 + (l & 31);
    const int d0 = ks * 16 + (l >> 5) * 8;
    const float* src = keys + ((size_t)e * DD + d0) * ESS + f;
    float v[8];
#pragma unroll
    for (int j = 0; j < 8; j++) v[j] = src[(size_t)j * ESS];
    uint4 r = { bpack(v[0], v[1]), bpack(v[2], v[3]), bpack(v[4], v[5]), bpack(v[6], v[7]) };
    const size_t off = (((size_t)e * 64 + ks) * 4 + nf) * 512 + l * 8;
    *(uint4*)(kfb + off) = r;
}

// ------------- values -> B-fragment-major bf16 -------------
// vfb[e][nv=0..31][ks=0..7][lane][j] = values[e][ks*16+(lane>>5)*8+j][nv*32+(lane&31)]
__global__ __launch_bounds__(512) void k_prep_v(const float* __restrict__ values,
                                                ushort* __restrict__ vfb) {
    const int e = blockIdx.x >> 5, nv = blockIdx.x & 31;
    const int ks = threadIdx.x >> 6, l = threadIdx.x & 63;
    const int v0 = nv * 32 + (l & 31);
    const int f0 = ks * 16 + (l >> 5) * 8;
    const float* src = values + ((size_t)e * ESS + f0) * VV + v0;
    float v[8];
#pragma unroll
    for (int j = 0; j < 8; j++) v[j] = src[(size_t)j * VV];
    uint4 r = { bpack(v[0], v[1]), bpack(v[2], v[3]), bpack(v[4], v[5]), bpack(v[6], v[7]) };
    const size_t off = (((size_t)e * 32 + nv) * 8 + ks) * 512 + l * 8;
    *(uint4*)(vfb + off) = r;
}

// ------------- router: sel_part[c] = X * Wsel^T over D-chunk c (fp32!) ----
// fp32 on purpose: bf16 logits flip ~1% of top-4 picks -> O(1) output errors.
// Split-D x4: grid (TT/64, 4) = 1024 blocks -> 4 blocks/CU (r5: 256 blocks =
// 1 wave/SIMD = latency-bound at 113us). Partials summed in k_token, fixed
// order (fp32 atomics would be run-to-run nondeterministic -> top-k flips).
__global__ __launch_bounds__(256) void k_router(const float* __restrict__ x,
                                                const float* __restrict__ sel,
                                                float* __restrict__ sel_part,
                                                uint* __restrict__ xbu) {
    __shared__ float xs[64][68];
    __shared__ float ss[32][68];
    const int tid = threadIdx.x;
    const int t0 = blockIdx.x * 64;
    const int dch = blockIdx.y;                 // D-chunk 0..3
    const int el = tid & 31;
    const int tg = tid >> 5;
    float acc[8];
#pragma unroll
    for (int i = 0; i < 8; i++) acc[i] = 0.f;

    for (int dc = dch * 256; dc < dch * 256 + 256; dc += 64) {
#pragma unroll
        for (int i = 0; i < 4; i++) {
            int q = tid + 256 * i;
            int r = q >> 4, c4 = q & 15;
            size_t gi = (size_t)(t0 + r) * DD + dc + c4 * 4;
            float4 v = *(const float4*)&x[gi];
            *(float4*)&xs[r][c4 * 4] = v;
            uint2 bv = { bpack(v.x, v.y), bpack(v.z, v.w) };   // fused bf16 emit
            *(uint2*)&xbu[gi / 2] = bv;
        }
#pragma unroll
        for (int i = 0; i < 2; i++) {
            int q = tid + 256 * i;
            int e = q >> 4, c4 = q & 15;
            float4 v = *(const float4*)&sel[(size_t)e * DD + dc + c4 * 4];
            *(float4*)&ss[e][c4 * 4] = v;
        }
        __syncthreads();
#pragma unroll
        for (int d4 = 0; d4 < 16; d4++) {
            float4 sv = *(const float4*)&ss[el][d4 * 4];
#pragma unroll
            for (int i = 0; i < 8; i++) {
                float4 xv = *(const float4*)&xs[tg * 8 + i][d4 * 4];
                acc[i] += xv.x * sv.x + xv.y * sv.y + xv.z * sv.z + xv.w * sv.w;
            }
        }
        __syncthreads();
    }
    float* dst = sel_part + (size_t)dch * TT * EE;
#pragma unroll
    for (int i = 0; i < 8; i++)
        dst[(size_t)(t0 + tg * 8 + i) * EE + el] = acc[i];
}

// ------------- per-token: sum partials, lse, sigmoid, top-4 ---------------
__global__ __launch_bounds__(256) void k_token(const float* __restrict__ sel_part,
                                               float* __restrict__ gates,
                                               int* __restrict__ idxs,
                                               float* __restrict__ lm_sums,
                                               int* __restrict__ counts) {
    __shared__ int hist[EE];
    __shared__ float lmh[EE];
    const int tid = threadIdx.x;
    if (tid < EE) { hist[tid] = 0; lmh[tid] = 0.f; }
    __syncthreads();

    const int t = blockIdx.x * 256 + tid;
    float v[32];
#pragma unroll
    for (int j = 0; j < 8; j++) {
        float4 q0 = *(const float4*)&sel_part[(size_t)t * EE + j * 4];
        float4 q1 = *(const float4*)&sel_part[((size_t)TT + t) * EE + j * 4];
        float4 q2 = *(const float4*)&sel_part[((size_t)2 * TT + t) * EE + j * 4];
        float4 q3 = *(const float4*)&sel_part[((size_t)3 * TT + t) * EE + j * 4];
        v[j * 4 + 0] = ((q0.x + q1.x) + (q2.x + q3.x));
        v[j * 4 + 1] = ((q0.y + q1.y) + (q2.y + q3.y));
        v[j * 4 + 2] = ((q0.z + q1.z) + (q2.z + q3.z));
        v[j * 4 + 3] = ((q0.w + q1.w) + (q2.w + q3.w));
    }
    float m = v[0];
#pragma unroll
    for (int e = 1; e < 32; e++) m = fmaxf(m, v[e]);
    float s = 0.f;
#pragma unroll
    for (int e = 0; e < 32; e++) s += expf(v[e] - m);
    const float lse = logf(s) + m;

    float sg[32];
#pragma unroll
    for (int e = 0; e < 32; e++) sg[e] = 1.f / (1.f + expf(-v[e]));

    unsigned taken = 0u;
#pragma unroll
    for (int k = 0; k < KK; k++) {
        float best = -1.f; int bi = 0;
#pragma unroll
        for (int e = 0; e < 32; e++) {
            bool free_e = !((taken >> e) & 1u);
            if (free_e && sg[e] > best) { best = sg[e]; bi = e; }
        }
        taken |= 1u << bi;
        gates[t * KK + k] = best;
        idxs[t * KK + k] = bi;
        atomicAdd(&hist[bi], 1);
    }

#pragma unroll
    for (int e = 0; e < 32; e++) {
        float pv = expf(v[e] - lse);
#pragma unroll
        for (int o = 32; o >= 1; o >>= 1) pv += __shfl_xor(pv, o, 64);
        if ((tid & 63) == 0) atomicAdd(&lmh[e], pv);
    }
    __syncthreads();
    if (tid < EE) {
        atomicAdd(&counts[tid], hist[tid]);
        atomicAdd(&lm_sums[tid], lmh[tid]);
    }
}

// ------------- wave-parallel: scan counts, tile map, reg_loss -------------
__global__ void k_scan(const int* __restrict__ counts, int* __restrict__ offsets,
                       int* __restrict__ cursors, int* __restrict__ tmape,
                       int* __restrict__ tmapt, int* __restrict__ ntiles,
                       const float* __restrict__ lm_sums, float* __restrict__ out_reg) {
    const int lane = threadIdx.x;          // one wave of 64
    int c = (lane < EE) ? counts[lane] : 0;
    int p = c;
#pragma unroll
    for (int o = 1; o < 32; o <<= 1) { int u = __shfl_up(p, o, 64); if (lane >= o) p += u; }
    const int off = p - c;                 // exclusive prefix
    if (lane < EE) { offsets[lane] = off; cursors[lane] = off; }
    if (lane == EE - 1) offsets[EE] = p;

    int nt = (c + TILE - 1) / TILE;
    int q = nt;
#pragma unroll
    for (int o = 1; o < 32; o <<= 1) { int u = __shfl_up(q, o, 64); if (lane >= o) q += u; }
    const int tb = q - nt;
    if (lane < EE)
        for (int j = 0; j < nt; j++) { tmape[tb + j] = lane; tmapt[tb + j] = j; }
    if (lane == EE - 1) ntiles[0] = q;

    float rv = 0.f;
    if (lane < EE) {
        float pe = lm_sums[lane] * (1.f / (float)TT);
        rv = pe * logf(pe);
    }
#pragma unroll
    for (int o = 16; o >= 1; o >>= 1) rv += __shfl_down(rv, o, 64);
    if (lane == 0) out_reg[0] = rv;
}

// ------------- scatter token ids into per-expert buckets (block-agg) ------
__global__ __launch_bounds__(256) void k_scatter(const int* __restrict__ idxs,
                                                 const float* __restrict__ gates,
                                                 int* __restrict__ cursors,
                                                 int* __restrict__ perm,
                                                 float* __restrict__ pgate,
                                                 int* __restrict__ islot) {
    __shared__ int lh[EE];
    __shared__ int lbase[EE];
    const int tid = threadIdx.x;
    if (tid < EE) lh[tid] = 0;
    __syncthreads();
    const int t = blockIdx.x * 256 + tid;
    int ee[KK], rk[KK];
#pragma unroll
    for (int k = 0; k < KK; k++) {
        ee[k] = idxs[t * KK + k];
        rk[k] = atomicAdd(&lh[ee[k]], 1);
    }
    __syncthreads();
    if (tid < EE) lbase[tid] = atomicAdd(&cursors[tid], lh[tid]);
    __syncthreads();
#pragma unroll
    for (int k = 0; k < KK; k++) {
        int pos = lbase[ee[k]] + rk[k];
        perm[pos] = t;
        pgate[pos] = gates[t * KK + k];
        islot[t * KK + k] = pos;
    }
}

// ------------- bucketed expert chain: 32x32x16 bf16 MFMA -------------
// phase 1: H[64][128] = relu(Xg * keys[e]) * gate  (waves 2x2: 32 tok x 64 f each)
//   X staged to LDS via global_load_lds (gathered rows, XOR-swizzled A reads);
//   B frag-major global stream with branchless 8-deep register prefetch.
// phase 2: OUT partials: STG=1 -> bf16 plain stores into per-slot staging
//   (no atomics; combine kernel reduces K slots/token); STG=0 -> fp32 atomics.
// A (32x32x16): row=lane&31, k=(lane>>5)*8+j.  B: col=lane&31, same k.
// C/D (m74/m101-verified): col=lane&31, row=(reg&3)+8*(reg>>2)+4*(lane>>5).
template <bool STG>
__global__ __launch_bounds__(256, 2) void k_expert(
    const ushort* __restrict__ xb, const ushort* __restrict__ kfb,
    const ushort* __restrict__ vfb,
    const int* __restrict__ perm, const float* __restrict__ pgate,
    const int* __restrict__ offsets, const int* __restrict__ counts,
    const int* __restrict__ tmape, const int* __restrict__ tmapt,
    const int* __restrict__ ntiles, ushort* __restrict__ stg,
    float* __restrict__ out)
{
    __shared__ __align__(1024) char xsb[64 * 512];  // X chunk: 64 rows x 256 cols bf16, swizzled
    __shared__ __align__(16) ushort hs[64][128];    // H bf16, XOR-swizzled cols
    __shared__ float gl[64];
    __shared__ int tl[64];

    // bijective XCD swizzle: 1056 = 8*132 -> per-XCD contiguous expert-major chunk
    const int bid = (blockIdx.x & 7) * 132 + (blockIdx.x >> 3);
    if (bid >= ntiles[0]) return;
    const int e = tmape[bid];
    const int base = offsets[e] + tmapt[bid] * TILE;
    const int nr = min(TILE, offsets[e] + counts[e] - base);
    const int tid = threadIdx.x;

    if (tid < 64) {
        int tok = 0; float g = 0.f;
        if (tid < nr) { tok = perm[base + tid]; g = pgate[base + tid]; }
        tl[tid] = tok; gl[tid] = g;
    }
    __syncthreads();

    const int lane = tid & 63, wid = tid >> 6;
    const int wm = wid >> 1, wn = wid & 1;      // 2x2 wave grid
    const int l31 = lane & 31, l5 = lane >> 5;

    const char* xbytes = (const char*)xb;
    const ushort* kb = kfb + ((size_t)e * 256 + wn * 2) * 512 + lane * 8;

    // per-lane staging geometry (2 rows per 1KB instruction)
    int srow[8]; const char* ssrc[8];
#pragma unroll
    for (int i = 0; i < 8; i++) {
        int ldsb = (wid * 8 + i) * 1024;
        int lb = ldsb + lane * 16;
        int row = lb >> 9;                      // /512
        int colb = lb & 511;
        srow[i] = ldsb;
        ssrc[i] = xbytes + (size_t)tl[row] * 2048 + (colb ^ ((row & 31) << 4));
    }

    f32x16 acc0, acc1;
#pragma unroll
    for (int r = 0; r < 16; r++) { acc0[r] = 0.f; acc1[r] = 0.f; }

    // 8-deep branchless B prefetch (ks = 0..63 global; wrap re-reads L2-hot lines)
    bf16x8 b0p[8], b1p[8];
#pragma unroll
    for (int j = 0; j < 8; j++) {
        b0p[j] = *(const bf16x8*)(kb + (size_t)j * 2048);
        b1p[j] = *(const bf16x8*)(kb + (size_t)j * 2048 + 512);
    }

    const int aRrow = wm * 32 + l31;            // A-frag row for this lane
    for (int c = 0; c < 4; c++) {
        // stage chunk c (cols c*256 .. +256)
#pragma unroll
        for (int i = 0; i < 8; i++)
            gload_lds16(ssrc[i] + c * 512, xsb + srow[i]);
        __syncthreads();                        // drains vmcnt -> chunk staged

#pragma unroll
        for (int ksl = 0; ksl < 16; ksl++) {
            bf16x8 a = *(const bf16x8*)(xsb + aRrow * 512 +
                                        ((ksl * 32 + l5 * 16) ^ (l31 << 4)));
            int ks = c * 16 + ksl;
            acc0 = __builtin_amdgcn_mfma_f32_32x32x16_bf16(a, b0p[ksl & 7], acc0, 0, 0, 0);
            acc1 = __builtin_amdgcn_mfma_f32_32x32x16_bf16(a, b1p[ksl & 7], acc1, 0, 0, 0);
            int nk = (ks + 8) & 63;             // branchless refill of the slot just used
            b0p[ksl & 7] = *(const bf16x8*)(kb + (size_t)nk * 2048);
            b1p[ksl & 7] = *(const bf16x8*)(kb + (size_t)nk * 2048 + 512);
        }
        __syncthreads();                        // all waves done reading xsb
    }

    // relu * gate -> swizzled bf16 H in LDS
#pragma unroll
    for (int r = 0; r < 16; r++) {
        int row = (r & 3) + 8 * (r >> 2) + 4 * l5;
        int grow = wm * 32 + row;
        float g = gl[grow];
        int c0 = wn * 64 + l31;
        int c1 = c0 + 32;
        int sw = (grow & 7) << 3;
        hs[grow][c0 ^ sw] = f2b(fmaxf(acc0[r], 0.f) * g);
        hs[grow][c1 ^ sw] = f2b(fmaxf(acc1[r], 0.f) * g);
    }
    __syncthreads();

    // ---- phase 2: A-frags (H) hoisted to regs, V double-buffered ----
    bf16x8 af[8];
    const int hr = wm * 32 + l31;
    const int hsw = (hr & 7) << 3;
#pragma unroll
    for (int ks = 0; ks < 8; ks++) {
        int cc = ks * 16 + l5 * 8;
        af[ks] = *(const bf16x8*)&hs[hr][cc ^ hsw];
    }

    int ptok[16]; int prow[16]; bool pv[16];
#pragma unroll
    for (int r = 0; r < 16; r++) {
        int row = wm * 32 + (r & 3) + 8 * (r >> 2) + 4 * l5;
        prow[r] = row; ptok[r] = tl[row]; pv[r] = (row < nr);
    }

    const ushort* vb = vfb + ((size_t)e * 32 + wn * 16) * 4096 + lane * 8;
    bf16x8 vp[2][8];
#pragma unroll
    for (int ks = 0; ks < 8; ks++) {
        vp[0][ks] = *(const bf16x8*)(vb + (size_t)ks * 512);
        vp[1][ks] = *(const bf16x8*)(vb + (size_t)(8 + ks) * 512);
    }

#pragma unroll
    for (int nv = 0; nv < 16; nv++) {
        f32x16 acc;
#pragma unroll
        for (int r = 0; r < 16; r++) acc[r] = 0.f;
#pragma unroll
        for (int ks = 0; ks < 8; ks++)
            acc = __builtin_amdgcn_mfma_f32_32x32x16_bf16(af[ks], vp[nv & 1][ks], acc, 0, 0, 0);
        if (nv + 2 < 16) {                      // refill the buffer just consumed
#pragma unroll
            for (int ks = 0; ks < 8; ks++)
                vp[nv & 1][ks] = *(const bf16x8*)(vb + ((size_t)(nv + 2) * 8 + ks) * 512);
        }
        const int colb = wn * 512 + nv * 32 + l31;
#pragma unroll
        for (int r = 0; r < 16; r++) {
            if (!pv[r]) continue;
            if (STG)
                stg[(size_t)(base + prow[r]) * VV + colb] = f2b(acc[r]);
            else
                atomicAdd(&out[(size_t)ptok[r] * VV + colb], acc[r]);
        }
    }
}

// ------------- combine: out[t] = sum_k stg[islot[t][k]]  (streaming) ------
__global__ __launch_bounds__(256) void k_combine(const ushort* __restrict__ stg,
                                                 const int* __restrict__ islot,
                                                 float* __restrict__ out) {
    const int tid = threadIdx.x;
    const int t = blockIdx.x * 2 + (tid >> 7);      // 2 tokens/block
    const int c8 = (tid & 127) * 8;                 // 8 cols per thread
    const int4 sl = *(const int4*)&islot[t * KK];
    float acc[8];
#pragma unroll
    for (int j = 0; j < 8; j++) acc[j] = 0.f;
    const int slots[4] = { sl.x, sl.y, sl.z, sl.w };
#pragma unroll
    for (int k = 0; k < KK; k++) {
        bf16x8 v = *(const bf16x8*)(stg + (size_t)slots[k] * VV + c8);
#pragma unroll
        for (int j = 0; j < 8; j++) acc[j] += b2f((ushort)v[j]);
    }
    float4 o0 = { acc[0], acc[1], acc[2], acc[3] };
    float4 o1 = { acc[4], acc[5], acc[6], acc[7] };
    *(float4*)&out[(size_t)t * VV + c8] = o0;
    *(float4*)&out[(size_t)t * VV + c8 + 4] = o1;
}

// --------------------------------------------------------------------------
extern "C" void kernel_launch(void* const* d_in, const int* in_sizes, int n_in,
                              void* d_out, int out_size, void* d_ws, size_t ws_size,
                              hipStream_t stream) {
    const float* x      = (const float*)d_in[0];
    const float* keys   = (const float*)d_in[1];
    const float* values = (const float*)d_in[2];
    const float* esel   = (const float*)d_in[3];
    float* out = (float*)d_out;

    float* wsf = (float*)d_ws;
    int*   wsi = (int*)d_ws;

    float* gates   = wsf + WS_GATES;
    float* pgate   = wsf + WS_PGATE;
    float* lm_sums = wsf + WS_LMSUMS;
    int*   counts  = wsi + WS_COUNTS;
    int*   offsets = wsi + WS_OFFSETS;
    int*   cursors = wsi + WS_CURSORS;
    int*   ntiles  = wsi + WS_NTILES;
    int*   tmape   = wsi + WS_TMAPE;
    int*   tmapt   = wsi + WS_TMAPT;
    int*   idxs    = wsi + WS_IDXS;
    int*   perm    = wsi + WS_PERM;
    int*   islot   = wsi + WS_ISLOT;
    uint*   xbu = (uint*)(wsf + WS_XB);
    ushort* xb  = (ushort*)xbu;
    ushort* kfb = (ushort*)(wsf + WS_KF);
    ushort* vfb = (ushort*)(wsf + WS_VF);
    ushort* stg = (ushort*)(wsf + WS_STG);

    const bool use_stg = ws_size >= WS_NEED_U * 4ull;
    // router partials alias a region that is only written LATER in the stream:
    // stg (k_expert) when staging, else kf (k_prep_k, launched after k_token).
    float* sel_part = use_stg ? (float*)stg : (float*)kfb;

    if (!use_stg)   // atomic fallback needs a zeroed accumulator
        hipMemsetAsync(d_out, 0, (size_t)TT * VV * sizeof(float), stream);
    hipMemsetAsync(wsf + WS_STATS, 0, 64 * sizeof(float), stream);

    k_router<<<dim3(TT / 64, 4), 256, 0, stream>>>(x, esel, sel_part, xbu);
    k_token<<<TT / 256, 256, 0, stream>>>(sel_part, gates, idxs, lm_sums, counts);

    k_prep_k<<<EE * 64, 256, 0, stream>>>(keys, kfb);
    k_prep_v<<<EE * 32, 512, 0, stream>>>(values, vfb);

    k_scan<<<1, 64, 0, stream>>>(counts, offsets, cursors, tmape, tmapt, ntiles,
                                 lm_sums, out + (size_t)TT * VV);
    k_scatter<<<TT / 256, 256, 0, stream>>>(idxs, gates, cursors, perm, pgate, islot);
    if (use_stg) {
        k_expert<true><<<NTILE_MAX, 256, 0, stream>>>(xb, kfb, vfb, perm, pgate,
                                                      offsets, counts, tmape, tmapt,
                                                      ntiles, stg, out);
        k_combine<<<TT / 2, 256, 0, stream>>>(stg, islot, out);
    } else {
        k_expert<false><<<NTILE_MAX, 256, 0, stream>>>(xb, kfb, vfb, perm, pgate,
                                                       offsets, counts, tmape, tmapt,
                                                       ntiles, stg, out);
    }
}

// Round 7
// 213.953 us; speedup vs baseline: 6.0291x; 1.0248x over previous
//
#include <hip/hip_runtime.h>

typedef unsigned int uint;
typedef unsigned short ushort;

#define TT 16384      // tokens = B*S
#define DD 1024       // d_model
#define EE 32         // experts
#define ESS 128       // expert size
#define VV 1024       // v dim
#define KK 4          // top-k
#define TILE 64
#define NTILE_MAX 1056   // 16384*4/64 + 32 ; == 8*132 (XCD-swizzle friendly)
#define RSPLIT 8         // router D-split

typedef __attribute__((ext_vector_type(8))) short bf16x8;   // 8 bf16 = 4 VGPR
typedef __attribute__((ext_vector_type(16))) float f32x16;

// ---------------- ws layout (offsets in 4B units) ----------------
#define WS_SELRAW   0                       // 524288 f (unused, layout stability)
#define WS_GATES    524288                  // 65536 f
#define WS_PGATE    589824                  // 65536 f
#define WS_STATS    655360                  // lm_sums 32 f + counts 32 i (memset region)
#define WS_LMSUMS   655360
#define WS_COUNTS   655392
#define WS_OFFSETS  655424                  // 33 i
#define WS_CURSORS  655457                  // 32 i
#define WS_NTILES   655489                  // 1 i
#define WS_TMAPE    655490                  // 1056 i
#define WS_TMAPT    656546                  // 1056 i
#define WS_IDXS     657602                  // 65536 i
#define WS_PERM     723138                  // 65536 i
// bf16 buffers (16B-aligned starts, sizes in uint units)
#define WS_XB       788736                  // x bf16 [16384][1024] -> 8388608 uints
#define WS_KF       9177344                 // keys frag-major [32][64][4][64][8] -> 2097152 uints
#define WS_VF       11274496                // values frag-major [32][32][8][64][8] -> 2097152 uints
#define WS_ISLOT    13371648                // token -> 4 slot ids, 65536 i
#define WS_STG      13437184                // slot partials bf16 [65536][1024] -> 33554432 uints
#define WS_NEED_U   46991616ull             // total uints needed for staging path
// router partials [RSPLIT][TT][EE] f32 (4194304 f) alias onto WS_STG (written later
// by k_expert) or, in the fallback, onto WS_KF..WS_VF (16MB contiguous, written
// later by k_prep_* which therefore launch AFTER k_token).

// fp32 -> bf16 RNE
__device__ __forceinline__ ushort f2b(float f) {
    uint u = __builtin_bit_cast(uint, f);
    u = (u + 0x7fffu + ((u >> 16) & 1u)) >> 16;
    return (ushort)u;
}
__device__ __forceinline__ uint bpack(float lo, float hi) {
    return (uint)f2b(lo) | ((uint)f2b(hi) << 16);
}
__device__ __forceinline__ float b2f(ushort b) {
    uint u = (uint)b << 16;
    return __builtin_bit_cast(float, u);
}

// async global->LDS, 16B per lane; LDS dest = wave-uniform base + lane*16,
// global src is per-lane (m104/m173 semantics)
__device__ __forceinline__ void gload_lds16(const void* g, void* l) {
    __builtin_amdgcn_global_load_lds(
        (const __attribute__((address_space(1))) uint*)g,
        (__attribute__((address_space(3))) uint*)l, 16, 0, 0);
}

// ------------- keys -> B-fragment-major bf16 -------------
// kfb[e][ks=0..63][nf=0..3][lane=0..63][j=0..7] = keys[e][ks*16+(lane>>5)*8+j][nf*32+(lane&31)]
__global__ __launch_bounds__(256) void k_prep_k(const float* __restrict__ keys,
                                                ushort* __restrict__ kfb) {
    const int e = blockIdx.x >> 6, ks = blockIdx.x & 63;
    const int nf = threadIdx.x >> 6, l = threadIdx.x & 63;
    const int f = nf * 32 + (l & 31);
    const int d0 = ks * 16 + (l >> 5) * 8;
    const float* src = keys + ((size_t)e * DD + d0) * ESS + f;
    float v[8];
#pragma unroll
    for (int j = 0; j < 8; j++) v[j] = src[(size_t)j * ESS];
    uint4 r = { bpack(v[0], v[1]), bpack(v[2], v[3]), bpack(v[4], v[5]), bpack(v[6], v[7]) };
    const size_t off = (((size_t)e * 64 + ks) * 4 + nf) * 512 + l * 8;
    *(uint4*)(kfb + off) = r;
}

// ------------- values -> B-fragment-major bf16 -------------
// vfb[e][nv=0..31][ks=0..7][lane][j] = values[e][ks*16+(lane>>5)*8+j][nv*32+(lane&31)]
__global__ __launch_bounds__(512) void k_prep_v(const float* __restrict__ values,
                                                ushort* __restrict__ vfb) {
    const int e = blockIdx.x >> 5, nv = blockIdx.x & 31;
    const int ks = threadIdx.x >> 6, l = threadIdx.x & 63;
    const int v0 = nv * 32 + (l & 31);
    const int f0 = ks * 16 + (l >> 5) * 8;
    const float* src = values + ((size_t)e * ESS + f0) * VV + v0;
    float v[8];
#pragma unroll
    for (int j = 0; j < 8; j++) v[j] = src[(size_t)j * VV];
    uint4 r = { bpack(v[0], v[1]), bpack(v[2], v[3]), bpack(v[4], v[5]), bpack(v[6], v[7]) };
    const size_t off = (((size_t)e * 32 + nv) * 8 + ks) * 512 + l * 8;
    *(uint4*)(vfb + off) = r;
}

// ------------- router: sel_part[c] = X * Wsel^T over D-chunk c (fp32!) ----
// fp32 on purpose: bf16 logits flip ~1% of top-4 picks -> O(1) output errors.
// Split-D x8: grid (TT/64, 8) = 2048 blocks -> 8 blocks/CU (r5: 256 blocks was
// latency-bound at 113us; r6 x4 helped, deepen). Partials summed in k_token in
// fixed order (fp32 atomics would be nondeterministic -> top-k flips).
__global__ __launch_bounds__(256) void k_router(const float* __restrict__ x,
                                                const float* __restrict__ sel,
                                                float* __restrict__ sel_part,
                                                uint* __restrict__ xbu) {
    __shared__ float xs[64][68];
    __shared__ float ss[32][68];
    const int tid = threadIdx.x;
    const int t0 = blockIdx.x * 64;
    const int dch = blockIdx.y;                 // D-chunk 0..RSPLIT-1
    const int el = tid & 31;
    const int tg = tid >> 5;
    float acc[8];
#pragma unroll
    for (int i = 0; i < 8; i++) acc[i] = 0.f;

    const int dlen = DD / RSPLIT;               // 128
    for (int dc = dch * dlen; dc < dch * dlen + dlen; dc += 64) {
#pragma unroll
        for (int i = 0; i < 4; i++) {
            int q = tid + 256 * i;
            int r = q >> 4, c4 = q & 15;
            size_t gi = (size_t)(t0 + r) * DD + dc + c4 * 4;
            float4 v = *(const float4*)&x[gi];
            *(float4*)&xs[r][c4 * 4] = v;
            uint2 bv = { bpack(v.x, v.y), bpack(v.z, v.w) };   // fused bf16 emit
            *(uint2*)&xbu[gi / 2] = bv;
        }
#pragma unroll
        for (int i = 0; i < 2; i++) {
            int q = tid + 256 * i;
            int e = q >> 4, c4 = q & 15;
            float4 v = *(const float4*)&sel[(size_t)e * DD + dc + c4 * 4];
            *(float4*)&ss[e][c4 * 4] = v;
        }
        __syncthreads();
#pragma unroll
        for (int d4 = 0; d4 < 16; d4++) {
            float4 sv = *(const float4*)&ss[el][d4 * 4];
#pragma unroll
            for (int i = 0; i < 8; i++) {
                float4 xv = *(const float4*)&xs[tg * 8 + i][d4 * 4];
                acc[i] += xv.x * sv.x + xv.y * sv.y + xv.z * sv.z + xv.w * sv.w;
            }
        }
        __syncthreads();
    }
    float* dst = sel_part + (size_t)dch * TT * EE;
#pragma unroll
    for (int i = 0; i < 8; i++)
        dst[(size_t)(t0 + tg * 8 + i) * EE + el] = acc[i];
}

// ------------- per-token: sum partials, lse, sigmoid, top-4 ---------------
__global__ __launch_bounds__(256) void k_token(const float* __restrict__ sel_part,
                                               float* __restrict__ gates,
                                               int* __restrict__ idxs,
                                               float* __restrict__ lm_sums,
                                               int* __restrict__ counts) {
    __shared__ int hist[EE];
    __shared__ float lmh[EE];
    const int tid = threadIdx.x;
    if (tid < EE) { hist[tid] = 0; lmh[tid] = 0.f; }
    __syncthreads();

    const int t = blockIdx.x * 256 + tid;
    float v[32];
#pragma unroll
    for (int j = 0; j < 8; j++) {
        float4 q[RSPLIT];
#pragma unroll
        for (int p = 0; p < RSPLIT; p++)
            q[p] = *(const float4*)&sel_part[((size_t)p * TT + t) * EE + j * 4];
        // fixed-order pairwise sum (determinism)
        v[j * 4 + 0] = ((q[0].x + q[1].x) + (q[2].x + q[3].x)) + ((q[4].x + q[5].x) + (q[6].x + q[7].x));
        v[j * 4 + 1] = ((q[0].y + q[1].y) + (q[2].y + q[3].y)) + ((q[4].y + q[5].y) + (q[6].y + q[7].y));
        v[j * 4 + 2] = ((q[0].z + q[1].z) + (q[2].z + q[3].z)) + ((q[4].z + q[5].z) + (q[6].z + q[7].z));
        v[j * 4 + 3] = ((q[0].w + q[1].w) + (q[2].w + q[3].w)) + ((q[4].w + q[5].w) + (q[6].w + q[7].w));
    }
    float m = v[0];
#pragma unroll
    for (int e = 1; e < 32; e++) m = fmaxf(m, v[e]);
    float s = 0.f;
#pragma unroll
    for (int e = 0; e < 32; e++) s += expf(v[e] - m);
    const float lse = logf(s) + m;

    float sg[32];
#pragma unroll
    for (int e = 0; e < 32; e++) sg[e] = 1.f / (1.f + expf(-v[e]));

    unsigned taken = 0u;
#pragma unroll
    for (int k = 0; k < KK; k++) {
        float best = -1.f; int bi = 0;
#pragma unroll
        for (int e = 0; e < 32; e++) {
            bool free_e = !((taken >> e) & 1u);
            if (free_e && sg[e] > best) { best = sg[e]; bi = e; }
        }
        taken |= 1u << bi;
        gates[t * KK + k] = best;
        idxs[t * KK + k] = bi;
        atomicAdd(&hist[bi], 1);
    }

#pragma unroll
    for (int e = 0; e < 32; e++) {
        float pv = expf(v[e] - lse);
#pragma unroll
        for (int o = 32; o >= 1; o >>= 1) pv += __shfl_xor(pv, o, 64);
        if ((tid & 63) == 0) atomicAdd(&lmh[e], pv);
    }
    __syncthreads();
    if (tid < EE) {
        atomicAdd(&counts[tid], hist[tid]);
        atomicAdd(&lm_sums[tid], lmh[tid]);
    }
}

// ------------- wave-parallel: scan counts, tile map, reg_loss -------------
__global__ void k_scan(const int* __restrict__ counts, int* __restrict__ offsets,
                       int* __restrict__ cursors, int* __restrict__ tmape,
                       int* __restrict__ tmapt, int* __restrict__ ntiles,
                       const float* __restrict__ lm_sums, float* __restrict__ out_reg) {
    const int lane = threadIdx.x;          // one wave of 64
    int c = (lane < EE) ? counts[lane] : 0;
    int p = c;
#pragma unroll
    for (int o = 1; o < 32; o <<= 1) { int u = __shfl_up(p, o, 64); if (lane >= o) p += u; }
    const int off = p - c;                 // exclusive prefix
    if (lane < EE) { offsets[lane] = off; cursors[lane] = off; }
    if (lane == EE - 1) offsets[EE] = p;

    int nt = (c + TILE - 1) / TILE;
    int q = nt;
#pragma unroll
    for (int o = 1; o < 32; o <<= 1) { int u = __shfl_up(q, o, 64); if (lane >= o) q += u; }
    const int tb = q - nt;
    if (lane < EE)
        for (int j = 0; j < nt; j++) { tmape[tb + j] = lane; tmapt[tb + j] = j; }
    if (lane == EE - 1) ntiles[0] = q;

    float rv = 0.f;
    if (lane < EE) {
        float pe = lm_sums[lane] * (1.f / (float)TT);
        rv = pe * logf(pe);
    }
#pragma unroll
    for (int o = 16; o >= 1; o >>= 1) rv += __shfl_down(rv, o, 64);
    if (lane == 0) out_reg[0] = rv;
}

// ------------- scatter token ids into per-expert buckets (block-agg) ------
__global__ __launch_bounds__(256) void k_scatter(const int* __restrict__ idxs,
                                                 const float* __restrict__ gates,
                                                 int* __restrict__ cursors,
                                                 int* __restrict__ perm,
                                                 float* __restrict__ pgate,
                                                 int* __restrict__ islot) {
    __shared__ int lh[EE];
    __shared__ int lbase[EE];
    const int tid = threadIdx.x;
    if (tid < EE) lh[tid] = 0;
    __syncthreads();
    const int t = blockIdx.x * 256 + tid;
    int ee[KK], rk[KK];
#pragma unroll
    for (int k = 0; k < KK; k++) {
        ee[k] = idxs[t * KK + k];
        rk[k] = atomicAdd(&lh[ee[k]], 1);
    }
    __syncthreads();
    if (tid < EE) lbase[tid] = atomicAdd(&cursors[tid], lh[tid]);
    __syncthreads();
#pragma unroll
    for (int k = 0; k < KK; k++) {
        int pos = lbase[ee[k]] + rk[k];
        perm[pos] = t;
        pgate[pos] = gates[t * KK + k];
        islot[t * KK + k] = pos;
    }
}

// ------------- bucketed expert chain: 32x32x16 bf16 MFMA -------------
// phase 1: H[64][128] = relu(Xg * keys[e]) * gate  (waves 2x2: 32 tok x 64 f each)
//   X staged in 128-col chunks, DOUBLE-BUFFERED (T3 2-phase: issue stage(c+1),
//   compute c, one barrier/chunk -> stage latency hides under MFMA).
//   XOR-swizzle ((row&15)<<4) on both source and ds_read (rule #21).
//   B frag-major global stream, 4-deep branchless register prefetch.
// phase 2: bf16 partials -> stg slots (plain stores; k_combine reduces), or
//   fp32 atomics in the no-workspace fallback.
// A (32x32x16): row=lane&31, k=(lane>>5)*8+j.  B: col=lane&31, same k.
// C/D (m74/m101-verified): col=lane&31, row=(reg&3)+8*(reg>>2)+4*(lane>>5).
template <bool STG>
__global__ __launch_bounds__(256, 3) void k_expert(
    const ushort* __restrict__ xb, const ushort* __restrict__ kfb,
    const ushort* __restrict__ vfb,
    const int* __restrict__ perm, const float* __restrict__ pgate,
    const int* __restrict__ offsets, const int* __restrict__ counts,
    const int* __restrict__ tmape, const int* __restrict__ tmapt,
    const int* __restrict__ ntiles, ushort* __restrict__ stg,
    float* __restrict__ out)
{
    __shared__ __align__(1024) char xsb[2][64 * 256]; // dbuf X: 64 rows x 128 cols bf16, swizzled
    __shared__ __align__(16) ushort hs[64][128];      // H bf16, XOR-swizzled cols
    __shared__ float gl[64];
    __shared__ int tl[64];

    // bijective XCD swizzle: 1056 = 8*132 -> per-XCD contiguous expert-major chunk
    const int bid = (blockIdx.x & 7) * 132 + (blockIdx.x >> 3);
    if (bid >= ntiles[0]) return;
    const int e = tmape[bid];
    const int base = offsets[e] + tmapt[bid] * TILE;
    const int nr = min(TILE, offsets[e] + counts[e] - base);
    const int tid = threadIdx.x;

    if (tid < 64) {
        int tok = 0; float g = 0.f;
        if (tid < nr) { tok = perm[base + tid]; g = pgate[base + tid]; }
        tl[tid] = tok; gl[tid] = g;
    }
    __syncthreads();

    const int lane = tid & 63, wid = tid >> 6;
    const int wm = wid >> 1, wn = wid & 1;      // 2x2 wave grid
    const int l31 = lane & 31, l5 = lane >> 5;

    const char* xbytes = (const char*)xb;
    const ushort* kb = kfb + ((size_t)e * 256 + wn * 2) * 512 + lane * 8;

    // staging geometry: per wave 4 instrs/chunk; instr i -> LDS [wid*4096+i*1024, +1KB)
    // lane byte = base + lane*16 -> row = wid*16 + i*4 + (lane>>4), colb = (lane&15)*16
    int srow[4]; const char* ssrc[4];
#pragma unroll
    for (int i = 0; i < 4; i++) {
        srow[i] = wid * 4096 + i * 1024;
        int row = wid * 16 + i * 4 + (lane >> 4);
        int colb = (lane & 15) * 16;
        ssrc[i] = xbytes + (size_t)tl[row] * 2048 + (colb ^ ((row & 15) << 4));
    }

    f32x16 acc0, acc1;
#pragma unroll
    for (int r = 0; r < 16; r++) { acc0[r] = 0.f; acc1[r] = 0.f; }

    // 4-deep branchless B prefetch (ks = 0..63 global; wrap re-reads L2-hot lines)
    bf16x8 b0p[4], b1p[4];
#pragma unroll
    for (int j = 0; j < 4; j++) {
        b0p[j] = *(const bf16x8*)(kb + (size_t)j * 2048);
        b1p[j] = *(const bf16x8*)(kb + (size_t)j * 2048 + 512);
    }

    const int hr = wm * 32 + l31;               // A-frag row for this lane
    const int asw = (hr & 15) << 4;             // byte swizzle for A reads

    // prologue: stage chunk 0 into buf 0
#pragma unroll
    for (int i = 0; i < 4; i++)
        gload_lds16(ssrc[i], xsb[0] + srow[i]);
    __syncthreads();

    for (int c = 0; c < 8; c++) {
        const int cur = c & 1;
        if (c < 7) {                            // issue next chunk into other buf
#pragma unroll
            for (int i = 0; i < 4; i++)
                gload_lds16(ssrc[i] + (c + 1) * 256, xsb[cur ^ 1] + srow[i]);
        }
        const char* xcur = xsb[cur];
#pragma unroll
        for (int ksl = 0; ksl < 8; ksl++) {
            bf16x8 a = *(const bf16x8*)(xcur + hr * 256 + ((ksl * 32 + l5 * 16) ^ asw));
            int ks = c * 8 + ksl;
            acc0 = __builtin_amdgcn_mfma_f32_32x32x16_bf16(a, b0p[ksl & 3], acc0, 0, 0, 0);
            acc1 = __builtin_amdgcn_mfma_f32_32x32x16_bf16(a, b1p[ksl & 3], acc1, 0, 0, 0);
            int nk = (ks + 4) & 63;             // branchless refill of slot just used
            b0p[ksl & 3] = *(const bf16x8*)(kb + (size_t)nk * 2048);
            b1p[ksl & 3] = *(const bf16x8*)(kb + (size_t)nk * 2048 + 512);
        }
        __syncthreads();   // readers done with cur + drain: next-chunk stages landed
    }

    // relu * gate -> swizzled bf16 H in LDS
#pragma unroll
    for (int r = 0; r < 16; r++) {
        int row = (r & 3) + 8 * (r >> 2) + 4 * l5;
        int grow = wm * 32 + row;
        float g = gl[grow];
        int c0 = wn * 64 + l31;
        int c1 = c0 + 32;
        int sw = (grow & 7) << 3;
        hs[grow][c0 ^ sw] = f2b(fmaxf(acc0[r], 0.f) * g);
        hs[grow][c1 ^ sw] = f2b(fmaxf(acc1[r], 0.f) * g);
    }
    __syncthreads();

    // ---- phase 2: A-frags (H) hoisted to regs, V half-buffer prefetch ----
    bf16x8 af[8];
    const int hsw = (hr & 7) << 3;
#pragma unroll
    for (int ks = 0; ks < 8; ks++) {
        int cc = ks * 16 + l5 * 8;
        af[ks] = *(const bf16x8*)&hs[hr][cc ^ hsw];
    }

    const ushort* vb = vfb + ((size_t)e * 32 + wn * 16) * 4096 + lane * 8;
    bf16x8 vpa[4], vpb[4];
#pragma unroll
    for (int j = 0; j < 4; j++) {
        vpa[j] = *(const bf16x8*)(vb + (size_t)j * 512);
        vpb[j] = *(const bf16x8*)(vb + (size_t)(4 + j) * 512);
    }

#pragma unroll
    for (int nv = 0; nv < 16; nv++) {
        f32x16 acc;
#pragma unroll
        for (int r = 0; r < 16; r++) acc[r] = 0.f;
#pragma unroll
        for (int ks = 0; ks < 4; ks++)
            acc = __builtin_amdgcn_mfma_f32_32x32x16_bf16(af[ks], vpa[ks], acc, 0, 0, 0);
        if (nv < 15) {                          // refill first half for nv+1
#pragma unroll
            for (int j = 0; j < 4; j++)
                vpa[j] = *(const bf16x8*)(vb + ((size_t)(nv + 1) * 8 + j) * 512);
        }
#pragma unroll
        for (int ks = 0; ks < 4; ks++)
            acc = __builtin_amdgcn_mfma_f32_32x32x16_bf16(af[4 + ks], vpb[ks], acc, 0, 0, 0);
        if (nv < 15) {                          // refill second half for nv+1
#pragma unroll
            for (int j = 0; j < 4; j++)
                vpb[j] = *(const bf16x8*)(vb + ((size_t)(nv + 1) * 8 + 4 + j) * 512);
        }
        const int colb = wn * 512 + nv * 32 + l31;
#pragma unroll
        for (int r = 0; r < 16; r++) {
            int row = wm * 32 + (r & 3) + 8 * (r >> 2) + 4 * l5;
            if (row < nr) {
                if (STG)
                    stg[(size_t)(base + row) * VV + colb] = f2b(acc[r]);
                else
                    atomicAdd(&out[(size_t)tl[row] * VV + colb], acc[r]);
            }
        }
    }
}

// ------------- combine: out[t] = sum_k stg[islot[t][k]]  (streaming) ------
__global__ __launch_bounds__(256) void k_combine(const ushort* __restrict__ stg,
                                                 const int* __restrict__ islot,
                                                 float* __restrict__ out) {
    const int tid = threadIdx.x;
    const int t = blockIdx.x * 2 + (tid >> 7);      // 2 tokens/block
    const int c8 = (tid & 127) * 8;                 // 8 cols per thread
    const int4 sl = *(const int4*)&islot[t * KK];
    float acc[8];
#pragma unroll
    for (int j = 0; j < 8; j++) acc[j] = 0.f;
    const int slots[4] = { sl.x, sl.y, sl.z, sl.w };
#pragma unroll
    for (int k = 0; k < KK; k++) {
        bf16x8 v = *(const bf16x8*)(stg + (size_t)slots[k] * VV + c8);
#pragma unroll
        for (int j = 0; j < 8; j++) acc[j] += b2f((ushort)v[j]);
    }
    float4 o0 = { acc[0], acc[1], acc[2], acc[3] };
    float4 o1 = { acc[4], acc[5], acc[6], acc[7] };
    *(float4*)&out[(size_t)t * VV + c8] = o0;
    *(float4*)&out[(size_t)t * VV + c8 + 4] = o1;
}

// --------------------------------------------------------------------------
extern "C" void kernel_launch(void* const* d_in, const int* in_sizes, int n_in,
                              void* d_out, int out_size, void* d_ws, size_t ws_size,
                              hipStream_t stream) {
    const float* x      = (const float*)d_in[0];
    const float* keys   = (const float*)d_in[1];
    const float* values = (const float*)d_in[2];
    const float* esel   = (const float*)d_in[3];
    float* out = (float*)d_out;

    float* wsf = (float*)d_ws;
    int*   wsi = (int*)d_ws;

    float* gates   = wsf + WS_GATES;
    float* pgate   = wsf + WS_PGATE;
    float* lm_sums = wsf + WS_LMSUMS;
    int*   counts  = wsi + WS_COUNTS;
    int*   offsets = wsi + WS_OFFSETS;
    int*   cursors = wsi + WS_CURSORS;
    int*   ntiles  = wsi + WS_NTILES;
    int*   tmape   = wsi + WS_TMAPE;
    int*   tmapt   = wsi + WS_TMAPT;
    int*   idxs    = wsi + WS_IDXS;
    int*   perm    = wsi + WS_PERM;
    int*   islot   = wsi + WS_ISLOT;
    uint*   xbu = (uint*)(wsf + WS_XB);
    ushort* xb  = (ushort*)xbu;
    ushort* kfb = (ushort*)(wsf + WS_KF);
    ushort* vfb = (ushort*)(wsf + WS_VF);
    ushort* stg = (ushort*)(wsf + WS_STG);

    const bool use_stg = ws_size >= WS_NEED_U * 4ull;
    // router partials alias a region only written LATER in the stream:
    // stg (k_expert) when staging, else kf+vf (k_prep_*, launched after k_token).
    float* sel_part = use_stg ? (float*)stg : (float*)kfb;

    if (!use_stg)   // atomic fallback needs a zeroed accumulator
        hipMemsetAsync(d_out, 0, (size_t)TT * VV * sizeof(float), stream);
    hipMemsetAsync(wsf + WS_STATS, 0, 64 * sizeof(float), stream);

    k_router<<<dim3(TT / 64, RSPLIT), 256, 0, stream>>>(x, esel, sel_part, xbu);
    k_token<<<TT / 256, 256, 0, stream>>>(sel_part, gates, idxs, lm_sums, counts);

    k_prep_k<<<EE * 64, 256, 0, stream>>>(keys, kfb);
    k_prep_v<<<EE * 32, 512, 0, stream>>>(values, vfb);

    k_scan<<<1, 64, 0, stream>>>(counts, offsets, cursors, tmape, tmapt, ntiles,
                                 lm_sums, out + (size_t)TT * VV);
    k_scatter<<<TT / 256, 256, 0, stream>>>(idxs, gates, cursors, perm, pgate, islot);
    if (use_stg) {
        k_expert<true><<<NTILE_MAX, 256, 0, stream>>>(xb, kfb, vfb, perm, pgate,
                                                      offsets, counts, tmape, tmapt,
                                                      ntiles, stg, out);
        k_combine<<<TT / 2, 256, 0, stream>>>(stg, islot, out);
    } else {
        k_expert<false><<<NTILE_MAX, 256, 0, stream>>>(xb, kfb, vfb, perm, pgate,
                                                       offsets, counts, tmape, tmapt,
                                                       ntiles, stg, out);
    }
}

// Round 8
// 212.284 us; speedup vs baseline: 6.0765x; 1.0079x over previous
//
#include <hip/hip_runtime.h>

typedef unsigned int uint;
typedef unsigned short ushort;

#define TT 16384      // tokens = B*S
#define DD 1024       // d_model
#define EE 32         // experts
#define ESS 128       // expert size
#define VV 1024       // v dim
#define KK 4          // top-k
#define TILE 64
#define NTILE_MAX 1056   // 16384*4/64 + 32 ; == 8*132 (XCD-swizzle friendly)
#define RSPLIT 8         // router D-split

typedef __attribute__((ext_vector_type(8))) short bf16x8;   // 8 bf16 = 4 VGPR
typedef __attribute__((ext_vector_type(16))) float f32x16;

// ---------------- ws layout (offsets in 4B units) ----------------
#define WS_SELRAW   0                       // 524288 f (unused, layout stability)
#define WS_GATES    524288                  // 65536 f
#define WS_PGATE    589824                  // 65536 f
#define WS_STATS    655360                  // lm_sums 32 f + counts 32 i (memset region)
#define WS_LMSUMS   655360
#define WS_COUNTS   655392
#define WS_OFFSETS  655424                  // 33 i
#define WS_CURSORS  655457                  // 32 i
#define WS_NTILES   655489                  // 1 i
#define WS_TMAPE    655490                  // 1056 i
#define WS_TMAPT    656546                  // 1056 i
#define WS_IDXS     657602                  // 65536 i
#define WS_PERM     723138                  // 65536 i
// bf16 buffers (16B-aligned starts, sizes in uint units)
#define WS_XB       788736                  // x bf16 [16384][1024] -> 8388608 uints
#define WS_KF       9177344                 // keys frag-major [32][64][4][64][8] -> 2097152 uints
#define WS_VF       11274496                // values frag-major [32][32][8][64][8] -> 2097152 uints
#define WS_ISLOT    13371648                // token -> 4 slot ids, 65536 i
#define WS_STG      13437184                // slot partials bf16 [65536][1024] -> 33554432 uints
#define WS_NEED_U   46991616ull             // total uints needed for staging path
// router partials [RSPLIT][TT][EE] f32 alias onto WS_STG (written later by
// k_expert) or, in the fallback, onto WS_KF..WS_VF (written later by k_prep_*,
// which therefore launch AFTER k_token).

// fp32 -> bf16 RNE
__device__ __forceinline__ ushort f2b(float f) {
    uint u = __builtin_bit_cast(uint, f);
    u = (u + 0x7fffu + ((u >> 16) & 1u)) >> 16;
    return (ushort)u;
}
__device__ __forceinline__ uint bpack(float lo, float hi) {
    return (uint)f2b(lo) | ((uint)f2b(hi) << 16);
}
__device__ __forceinline__ float b2f(ushort b) {
    uint u = (uint)b << 16;
    return __builtin_bit_cast(float, u);
}

// async global->LDS, 16B per lane; LDS dest = wave-uniform base + lane*16,
// global src is per-lane (m104/m173 semantics)
__device__ __forceinline__ void gload_lds16(const void* g, void* l) {
    __builtin_amdgcn_global_load_lds(
        (const __attribute__((address_space(1))) uint*)g,
        (__attribute__((address_space(3))) uint*)l, 16, 0, 0);
}

// ------------- keys -> B-fragment-major bf16 -------------
// kfb[e][ks=0..63][nf=0..3][lane=0..63][j=0..7] = keys[e][ks*16+(lane>>5)*8+j][nf*32+(lane&31)]
__global__ __launch_bounds__(256) void k_prep_k(const float* __restrict__ keys,
                                                ushort* __restrict__ kfb) {
    const int e = blockIdx.x >> 6, ks = blockIdx.x & 63;
    const int nf = threadIdx.x >> 6, l = threadIdx.x & 63;
    const int f = nf * 32 + (l & 31);
    const int d0 = ks * 16 + (l >> 5) * 8;
    const float* src = keys + ((size_t)e * DD + d0) * ESS + f;
    float v[8];
#pragma unroll
    for (int j = 0; j < 8; j++) v[j] = src[(size_t)j * ESS];
    uint4 r = { bpack(v[0], v[1]), bpack(v[2], v[3]), bpack(v[4], v[5]), bpack(v[6], v[7]) };
    const size_t off = (((size_t)e * 64 + ks) * 4 + nf) * 512 + l * 8;
    *(uint4*)(kfb + off) = r;
}

// ------------- values -> B-fragment-major bf16 -------------
// vfb[e][nv=0..31][ks=0..7][lane][j] = values[e][ks*16+(lane>>5)*8+j][nv*32+(lane&31)]
__global__ __launch_bounds__(512) void k_prep_v(const float* __restrict__ values,
                                                ushort* __restrict__ vfb) {
    const int e = blockIdx.x >> 5, nv = blockIdx.x & 31;
    const int ks = threadIdx.x >> 6, l = threadIdx.x & 63;
    const int v0 = nv * 32 + (l & 31);
    const int f0 = ks * 16 + (l >> 5) * 8;
    const float* src = values + ((size_t)e * ESS + f0) * VV + v0;
    float v[8];
#pragma unroll
    for (int j = 0; j < 8; j++) v[j] = src[(size_t)j * VV];
    uint4 r = { bpack(v[0], v[1]), bpack(v[2], v[3]), bpack(v[4], v[5]), bpack(v[6], v[7]) };
    const size_t off = (((size_t)e * 32 + nv) * 8 + ks) * 512 + l * 8;
    *(uint4*)(vfb + off) = r;
}

// ------------- router: sel_part[c] = X * Wsel^T over D-chunk c (fp32!) ----
// fp32 on purpose: bf16 logits flip ~1% of top-4 picks -> O(1) output errors.
__global__ __launch_bounds__(256) void k_router(const float* __restrict__ x,
                                                const float* __restrict__ sel,
                                                float* __restrict__ sel_part,
                                                uint* __restrict__ xbu) {
    __shared__ float xs[64][68];
    __shared__ float ss[32][68];
    const int tid = threadIdx.x;
    const int t0 = blockIdx.x * 64;
    const int dch = blockIdx.y;                 // D-chunk 0..RSPLIT-1
    const int el = tid & 31;
    const int tg = tid >> 5;
    float acc[8];
#pragma unroll
    for (int i = 0; i < 8; i++) acc[i] = 0.f;

    const int dlen = DD / RSPLIT;               // 128
    for (int dc = dch * dlen; dc < dch * dlen + dlen; dc += 64) {
#pragma unroll
        for (int i = 0; i < 4; i++) {
            int q = tid + 256 * i;
            int r = q >> 4, c4 = q & 15;
            size_t gi = (size_t)(t0 + r) * DD + dc + c4 * 4;
            float4 v = *(const float4*)&x[gi];
            *(float4*)&xs[r][c4 * 4] = v;
            uint2 bv = { bpack(v.x, v.y), bpack(v.z, v.w) };   // fused bf16 emit
            *(uint2*)&xbu[gi / 2] = bv;
        }
#pragma unroll
        for (int i = 0; i < 2; i++) {
            int q = tid + 256 * i;
            int e = q >> 4, c4 = q & 15;
            float4 v = *(const float4*)&sel[(size_t)e * DD + dc + c4 * 4];
            *(float4*)&ss[e][c4 * 4] = v;
        }
        __syncthreads();
#pragma unroll
        for (int d4 = 0; d4 < 16; d4++) {
            float4 sv = *(const float4*)&ss[el][d4 * 4];
#pragma unroll
            for (int i = 0; i < 8; i++) {
                float4 xv = *(const float4*)&xs[tg * 8 + i][d4 * 4];
                acc[i] += xv.x * sv.x + xv.y * sv.y + xv.z * sv.z + xv.w * sv.w;
            }
        }
        __syncthreads();
    }
    float* dst = sel_part + (size_t)dch * TT * EE;
#pragma unroll
    for (int i = 0; i < 8; i++)
        dst[(size_t)(t0 + tg * 8 + i) * EE + el] = acc[i];
}

// ------------- per-token: sum partials, lse, sigmoid, top-4 ---------------
__global__ __launch_bounds__(256) void k_token(const float* __restrict__ sel_part,
                                               float* __restrict__ gates,
                                               int* __restrict__ idxs,
                                               float* __restrict__ lm_sums,
                                               int* __restrict__ counts) {
    __shared__ int hist[EE];
    __shared__ float lmh[EE];
    const int tid = threadIdx.x;
    if (tid < EE) { hist[tid] = 0; lmh[tid] = 0.f; }
    __syncthreads();

    const int t = blockIdx.x * 256 + tid;
    float v[32];
#pragma unroll
    for (int j = 0; j < 8; j++) {
        float4 q[RSPLIT];
#pragma unroll
        for (int p = 0; p < RSPLIT; p++)
            q[p] = *(const float4*)&sel_part[((size_t)p * TT + t) * EE + j * 4];
        // fixed-order pairwise sum (determinism)
        v[j * 4 + 0] = ((q[0].x + q[1].x) + (q[2].x + q[3].x)) + ((q[4].x + q[5].x) + (q[6].x + q[7].x));
        v[j * 4 + 1] = ((q[0].y + q[1].y) + (q[2].y + q[3].y)) + ((q[4].y + q[5].y) + (q[6].y + q[7].y));
        v[j * 4 + 2] = ((q[0].z + q[1].z) + (q[2].z + q[3].z)) + ((q[4].z + q[5].z) + (q[6].z + q[7].z));
        v[j * 4 + 3] = ((q[0].w + q[1].w) + (q[2].w + q[3].w)) + ((q[4].w + q[5].w) + (q[6].w + q[7].w));
    }
    float m = v[0];
#pragma unroll
    for (int e = 1; e < 32; e++) m = fmaxf(m, v[e]);
    float s = 0.f;
#pragma unroll
    for (int e = 0; e < 32; e++) s += expf(v[e] - m);
    const float lse = logf(s) + m;

    float sg[32];
#pragma unroll
    for (int e = 0; e < 32; e++) sg[e] = 1.f / (1.f + expf(-v[e]));

    unsigned taken = 0u;
#pragma unroll
    for (int k = 0; k < KK; k++) {
        float best = -1.f; int bi = 0;
#pragma unroll
        for (int e = 0; e < 32; e++) {
            bool free_e = !((taken >> e) & 1u);
            if (free_e && sg[e] > best) { best = sg[e]; bi = e; }
        }
        taken |= 1u << bi;
        gates[t * KK + k] = best;
        idxs[t * KK + k] = bi;
        atomicAdd(&hist[bi], 1);
    }

#pragma unroll
    for (int e = 0; e < 32; e++) {
        float pv = expf(v[e] - lse);
#pragma unroll
        for (int o = 32; o >= 1; o >>= 1) pv += __shfl_xor(pv, o, 64);
        if ((tid & 63) == 0) atomicAdd(&lmh[e], pv);
    }
    __syncthreads();
    if (tid < EE) {
        atomicAdd(&counts[tid], hist[tid]);
        atomicAdd(&lm_sums[tid], lmh[tid]);
    }
}

// ------------- wave-parallel: scan counts, tile map, reg_loss -------------
__global__ void k_scan(const int* __restrict__ counts, int* __restrict__ offsets,
                       int* __restrict__ cursors, int* __restrict__ tmape,
                       int* __restrict__ tmapt, int* __restrict__ ntiles,
                       const float* __restrict__ lm_sums, float* __restrict__ out_reg) {
    const int lane = threadIdx.x;          // one wave of 64
    int c = (lane < EE) ? counts[lane] : 0;
    int p = c;
#pragma unroll
    for (int o = 1; o < 32; o <<= 1) { int u = __shfl_up(p, o, 64); if (lane >= o) p += u; }
    const int off = p - c;                 // exclusive prefix
    if (lane < EE) { offsets[lane] = off; cursors[lane] = off; }
    if (lane == EE - 1) offsets[EE] = p;

    int nt = (c + TILE - 1) / TILE;
    int q = nt;
#pragma unroll
    for (int o = 1; o < 32; o <<= 1) { int u = __shfl_up(q, o, 64); if (lane >= o) q += u; }
    const int tb = q - nt;
    if (lane < EE)
        for (int j = 0; j < nt; j++) { tmape[tb + j] = lane; tmapt[tb + j] = j; }
    if (lane == EE - 1) ntiles[0] = q;

    float rv = 0.f;
    if (lane < EE) {
        float pe = lm_sums[lane] * (1.f / (float)TT);
        rv = pe * logf(pe);
    }
#pragma unroll
    for (int o = 16; o >= 1; o >>= 1) rv += __shfl_down(rv, o, 64);
    if (lane == 0) out_reg[0] = rv;
}

// ------------- scatter token ids into per-expert buckets (block-agg) ------
__global__ __launch_bounds__(256) void k_scatter(const int* __restrict__ idxs,
                                                 const float* __restrict__ gates,
                                                 int* __restrict__ cursors,
                                                 int* __restrict__ perm,
                                                 float* __restrict__ pgate,
                                                 int* __restrict__ islot) {
    __shared__ int lh[EE];
    __shared__ int lbase[EE];
    const int tid = threadIdx.x;
    if (tid < EE) lh[tid] = 0;
    __syncthreads();
    const int t = blockIdx.x * 256 + tid;
    int ee[KK], rk[KK];
#pragma unroll
    for (int k = 0; k < KK; k++) {
        ee[k] = idxs[t * KK + k];
        rk[k] = atomicAdd(&lh[ee[k]], 1);
    }
    __syncthreads();
    if (tid < EE) lbase[tid] = atomicAdd(&cursors[tid], lh[tid]);
    __syncthreads();
#pragma unroll
    for (int k = 0; k < KK; k++) {
        int pos = lbase[ee[k]] + rk[k];
        perm[pos] = t;
        pgate[pos] = gates[t * KK + k];
        islot[t * KK + k] = pos;
    }
}

// ------------- bucketed expert chain: 32x32x16 bf16 MFMA -------------
// phase 1: H[64][128] = relu(Xg * keys[e]) * gate  (waves 2x2: 32 tok x 64 f each)
//   X double-buffered 128-col chunks via global_load_lds; B frag-major stream
//   with 8-deep register prefetch (covers ~200cy L2 latency); per-chunk barrier
//   uses COUNTED s_waitcnt vmcnt(16) (T4): stage loads are the 4 OLDEST
//   outstanding VMEM ops (issued at body top, B-refills after), so vmcnt(16)
//   retires exactly the stage while 16 B-refills stay in flight across the
//   barrier. Plain __syncthreads would vmcnt(0)-drain the prefetch every chunk
//   (r6/r7: MfmaUtil pinned at 16%).
// phase 2: bf16 partials -> stg slots (plain stores; k_combine reduces), or
//   fp32 atomics in the no-workspace fallback.
// A (32x32x16): row=lane&31, k=(lane>>5)*8+j.  B: col=lane&31, same k.
// C/D (m74/m101-verified): col=lane&31, row=(reg&3)+8*(reg>>2)+4*(lane>>5).
template <bool STG>
__global__ __launch_bounds__(256, 3) void k_expert(
    const ushort* __restrict__ xb, const ushort* __restrict__ kfb,
    const ushort* __restrict__ vfb,
    const int* __restrict__ perm, const float* __restrict__ pgate,
    const int* __restrict__ offsets, const int* __restrict__ counts,
    const int* __restrict__ tmape, const int* __restrict__ tmapt,
    const int* __restrict__ ntiles, ushort* __restrict__ stg,
    float* __restrict__ out)
{
    __shared__ __align__(1024) char xsb[2][64 * 256]; // dbuf X: 64 rows x 128 cols bf16, swizzled
    __shared__ __align__(16) ushort hs[64][128];      // H bf16, XOR-swizzled cols
    __shared__ float gl[64];
    __shared__ int tl[64];

    // bijective XCD swizzle: 1056 = 8*132 -> per-XCD contiguous expert-major chunk
    const int bid = (blockIdx.x & 7) * 132 + (blockIdx.x >> 3);
    if (bid >= ntiles[0]) return;
    const int e = tmape[bid];
    const int base = offsets[e] + tmapt[bid] * TILE;
    const int nr = min(TILE, offsets[e] + counts[e] - base);
    const int tid = threadIdx.x;

    if (tid < 64) {
        int tok = 0; float g = 0.f;
        if (tid < nr) { tok = perm[base + tid]; g = pgate[base + tid]; }
        tl[tid] = tok; gl[tid] = g;
    }
    __syncthreads();

    const int lane = tid & 63, wid = tid >> 6;
    const int wm = wid >> 1, wn = wid & 1;      // 2x2 wave grid
    const int l31 = lane & 31, l5 = lane >> 5;

    const char* xbytes = (const char*)xb;
    const ushort* kb = kfb + ((size_t)e * 256 + wn * 2) * 512 + lane * 8;

    // staging geometry: per wave 4 instrs/chunk; instr i -> LDS [wid*4096+i*1024, +1KB)
    int srow[4]; const char* ssrc[4];
#pragma unroll
    for (int i = 0; i < 4; i++) {
        srow[i] = wid * 4096 + i * 1024;
        int row = wid * 16 + i * 4 + (lane >> 4);
        int colb = (lane & 15) * 16;
        ssrc[i] = xbytes + (size_t)tl[row] * 2048 + (colb ^ ((row & 15) << 4));
    }

    f32x16 acc0, acc1;
#pragma unroll
    for (int r = 0; r < 16; r++) { acc0[r] = 0.f; acc1[r] = 0.f; }

    // prologue: stage chunk 0 FIRST (oldest vmem), then 8-deep B prefetch init
#pragma unroll
    for (int i = 0; i < 4; i++)
        gload_lds16(ssrc[i], xsb[0] + srow[i]);

    bf16x8 b0p[8], b1p[8];
#pragma unroll
    for (int j = 0; j < 8; j++) {
        b0p[j] = *(const bf16x8*)(kb + (size_t)j * 2048);
        b1p[j] = *(const bf16x8*)(kb + (size_t)j * 2048 + 512);
    }
    // stage(0) = 4 oldest of 20 outstanding -> vmcnt(16) retires it, keeps B in flight
    asm volatile("s_waitcnt vmcnt(16)" ::: "memory");
    __builtin_amdgcn_s_barrier();
    __builtin_amdgcn_sched_barrier(0);

    const int hr = wm * 32 + l31;               // A-frag row for this lane
    const int asw = (hr & 15) << 4;             // byte swizzle for A reads

    for (int c = 0; c < 8; c++) {
        const int cur = c & 1;
        if (c < 7) {                            // issue next chunk into other buf (oldest vmem of this body)
#pragma unroll
            for (int i = 0; i < 4; i++)
                gload_lds16(ssrc[i] + (c + 1) * 256, xsb[cur ^ 1] + srow[i]);
        }
        const char* xcur = xsb[cur];
#pragma unroll
        for (int ksl = 0; ksl < 8; ksl++) {
            bf16x8 a = *(const bf16x8*)(xcur + hr * 256 + ((ksl * 32 + l5 * 16) ^ asw));
            int ks = c * 8 + ksl;
            acc0 = __builtin_amdgcn_mfma_f32_32x32x16_bf16(a, b0p[ksl], acc0, 0, 0, 0);
            acc1 = __builtin_amdgcn_mfma_f32_32x32x16_bf16(a, b1p[ksl], acc1, 0, 0, 0);
            int nk = (ks + 8) & 63;             // branchless refill of slot just used
            b0p[ksl] = *(const bf16x8*)(kb + (size_t)nk * 2048);
            b1p[ksl] = *(const bf16x8*)(kb + (size_t)nk * 2048 + 512);
        }
        // counted barrier: retire the 4 stage loads (oldest), keep 16 B-refills in flight
        asm volatile("s_waitcnt vmcnt(16)" ::: "memory");
        __builtin_amdgcn_s_barrier();
        __builtin_amdgcn_sched_barrier(0);
    }

    // relu * gate -> swizzled bf16 H in LDS
#pragma unroll
    for (int r = 0; r < 16; r++) {
        int row = (r & 3) + 8 * (r >> 2) + 4 * l5;
        int grow = wm * 32 + row;
        float g = gl[grow];
        int c0 = wn * 64 + l31;
        int c1 = c0 + 32;
        int sw = (grow & 7) << 3;
        hs[grow][c0 ^ sw] = f2b(fmaxf(acc0[r], 0.f) * g);
        hs[grow][c1 ^ sw] = f2b(fmaxf(acc1[r], 0.f) * g);
    }
    __syncthreads();

    // ---- phase 2: A-frags (H) hoisted to regs, V half-buffer prefetch ----
    bf16x8 af[8];
    const int hsw = (hr & 7) << 3;
#pragma unroll
    for (int ks = 0; ks < 8; ks++) {
        int cc = ks * 16 + l5 * 8;
        af[ks] = *(const bf16x8*)&hs[hr][cc ^ hsw];
    }

    const ushort* vb = vfb + ((size_t)e * 32 + wn * 16) * 4096 + lane * 8;
    bf16x8 vpa[4], vpb[4];
#pragma unroll
    for (int j = 0; j < 4; j++) {
        vpa[j] = *(const bf16x8*)(vb + (size_t)j * 512);
        vpb[j] = *(const bf16x8*)(vb + (size_t)(4 + j) * 512);
    }

#pragma unroll
    for (int nv = 0; nv < 16; nv++) {
        f32x16 acc;
#pragma unroll
        for (int r = 0; r < 16; r++) acc[r] = 0.f;
#pragma unroll
        for (int ks = 0; ks < 4; ks++)
            acc = __builtin_amdgcn_mfma_f32_32x32x16_bf16(af[ks], vpa[ks], acc, 0, 0, 0);
        if (nv < 15) {                          // refill first half for nv+1
#pragma unroll
            for (int j = 0; j < 4; j++)
                vpa[j] = *(const bf16x8*)(vb + ((size_t)(nv + 1) * 8 + j) * 512);
        }
#pragma unroll
        for (int ks = 0; ks < 4; ks++)
            acc = __builtin_amdgcn_mfma_f32_32x32x16_bf16(af[4 + ks], vpb[ks], acc, 0, 0, 0);
        if (nv < 15) {                          // refill second half for nv+1
#pragma unroll
            for (int j = 0; j < 4; j++)
                vpb[j] = *(const bf16x8*)(vb + ((size_t)(nv + 1) * 8 + 4 + j) * 512);
        }
        const int colb = wn * 512 + nv * 32 + l31;
#pragma unroll
        for (int r = 0; r < 16; r++) {
            int row = wm * 32 + (r & 3) + 8 * (r >> 2) + 4 * l5;
            if (row < nr) {
                if (STG)
                    stg[(size_t)(base + row) * VV + colb] = f2b(acc[r]);
                else
                    atomicAdd(&out[(size_t)tl[row] * VV + colb], acc[r]);
            }
        }
    }
}

// ------------- combine: out[t] = sum_k stg[islot[t][k]]  (streaming) ------
__global__ __launch_bounds__(256) void k_combine(const ushort* __restrict__ stg,
                                                 const int* __restrict__ islot,
                                                 float* __restrict__ out) {
    const int tid = threadIdx.x;
    const int t = blockIdx.x * 2 + (tid >> 7);      // 2 tokens/block
    const int c8 = (tid & 127) * 8;                 // 8 cols per thread
    const int4 sl = *(const int4*)&islot[t * KK];
    float acc[8];
#pragma unroll
    for (int j = 0; j < 8; j++) acc[j] = 0.f;
    const int slots[4] = { sl.x, sl.y, sl.z, sl.w };
#pragma unroll
    for (int k = 0; k < KK; k++) {
        bf16x8 v = *(const bf16x8*)(stg + (size_t)slots[k] * VV + c8);
#pragma unroll
        for (int j = 0; j < 8; j++) acc[j] += b2f((ushort)v[j]);
    }
    float4 o0 = { acc[0], acc[1], acc[2], acc[3] };
    float4 o1 = { acc[4], acc[5], acc[6], acc[7] };
    *(float4*)&out[(size_t)t * VV + c8] = o0;
    *(float4*)&out[(size_t)t * VV + c8 + 4] = o1;
}

// --------------------------------------------------------------------------
extern "C" void kernel_launch(void* const* d_in, const int* in_sizes, int n_in,
                              void* d_out, int out_size, void* d_ws, size_t ws_size,
                              hipStream_t stream) {
    const float* x      = (const float*)d_in[0];
    const float* keys   = (const float*)d_in[1];
    const float* values = (const float*)d_in[2];
    const float* esel   = (const float*)d_in[3];
    float* out = (float*)d_out;

    float* wsf = (float*)d_ws;
    int*   wsi = (int*)d_ws;

    float* gates   = wsf + WS_GATES;
    float* pgate   = wsf + WS_PGATE;
    float* lm_sums = wsf + WS_LMSUMS;
    int*   counts  = wsi + WS_COUNTS;
    int*   offsets = wsi + WS_OFFSETS;
    int*   cursors = wsi + WS_CURSORS;
    int*   ntiles  = wsi + WS_NTILES;
    int*   tmape   = wsi + WS_TMAPE;
    int*   tmapt   = wsi + WS_TMAPT;
    int*   idxs    = wsi + WS_IDXS;
    int*   perm    = wsi + WS_PERM;
    int*   islot   = wsi + WS_ISLOT;
    uint*   xbu = (uint*)(wsf + WS_XB);
    ushort* xb  = (ushort*)xbu;
    ushort* kfb = (ushort*)(wsf + WS_KF);
    ushort* vfb = (ushort*)(wsf + WS_VF);
    ushort* stg = (ushort*)(wsf + WS_STG);

    const bool use_stg = ws_size >= WS_NEED_U * 4ull;
    // router partials alias a region only written LATER in the stream:
    // stg (k_expert) when staging, else kf+vf (k_prep_*, launched after k_token).
    float* sel_part = use_stg ? (float*)stg : (float*)kfb;

    if (!use_stg)   // atomic fallback needs a zeroed accumulator
        hipMemsetAsync(d_out, 0, (size_t)TT * VV * sizeof(float), stream);
    hipMemsetAsync(wsf + WS_STATS, 0, 64 * sizeof(float), stream);

    k_router<<<dim3(TT / 64, RSPLIT), 256, 0, stream>>>(x, esel, sel_part, xbu);
    k_token<<<TT / 256, 256, 0, stream>>>(sel_part, gates, idxs, lm_sums, counts);

    k_prep_k<<<EE * 64, 256, 0, stream>>>(keys, kfb);
    k_prep_v<<<EE * 32, 512, 0, stream>>>(values, vfb);

    k_scan<<<1, 64, 0, stream>>>(counts, offsets, cursors, tmape, tmapt, ntiles,
                                 lm_sums, out + (size_t)TT * VV);
    k_scatter<<<TT / 256, 256, 0, stream>>>(idxs, gates, cursors, perm, pgate, islot);
    if (use_stg) {
        k_expert<true><<<NTILE_MAX, 256, 0, stream>>>(xb, kfb, vfb, perm, pgate,
                                                      offsets, counts, tmape, tmapt,
                                                      ntiles, stg, out);
        k_combine<<<TT / 2, 256, 0, stream>>>(stg, islot, out);
    } else {
        k_expert<false><<<NTILE_MAX, 256, 0, stream>>>(xb, kfb, vfb, perm, pgate,
                                                       offsets, counts, tmape, tmapt,
                                                       ntiles, stg, out);
    }
}